// Round 8
// baseline (242.721 us; speedup 1.0000x reference)
//
#include <hip/hip_runtime.h>
#include <hip/hip_bf16.h>
#include <cstdint>
#include <cstddef>

#define T_DIM 2048
#define C_DIM 1024
#define NH 16
#define HS 64
#define KSP 64

// 128x128 GEMM tile, BK=64, 4 waves x (64x64 out = 4x4 accs of 16x16)
#define GBM 128
#define GBN 128
#define GBK 64
#define GPAD 72  // 64+8 elems -> 144B row stride; frag reads 2-way alias (free)

typedef short short8 __attribute__((ext_vector_type(8)));
typedef float f32x4 __attribute__((ext_vector_type(4)));

__device__ __forceinline__ float bfu2f(unsigned short u) {
  unsigned v = ((unsigned)u) << 16;
  return __builtin_bit_cast(float, v);
}
__device__ __forceinline__ unsigned short f2bfu(float f) {
  unsigned u = __builtin_bit_cast(unsigned, f);
  unsigned r = (u + 0x7fffu + ((u >> 16) & 1u)) >> 16;
  return (unsigned short)r;
}

// ---- fused float32 -> bf16 conversion of x + 4 weight matrices ----
__global__ __launch_bounds__(256) void convert_all_kernel(
    const float* __restrict__ x, const float* __restrict__ Wq,
    const float* __restrict__ Wk, const float* __restrict__ Wv,
    const float* __restrict__ Wo,
    unsigned short* __restrict__ xb, unsigned short* __restrict__ Wqb,
    unsigned short* __restrict__ Wkb, unsigned short* __restrict__ Wvb,
    unsigned short* __restrict__ Wob) {
  const int i = blockIdx.x * 256 + threadIdx.x;
  const int NX4 = T_DIM * C_DIM / 4;
  const int NW4 = C_DIM * C_DIM / 4;
  const float* src;
  unsigned short* dst;
  int j = i;
  if (j < NX4) { src = x; dst = xb; }
  else {
    j -= NX4;
    int w = j / NW4;
    j -= w * NW4;
    src = (w == 0) ? Wq : (w == 1) ? Wk : (w == 2) ? Wv : Wo;
    dst = (w == 0) ? Wqb : (w == 1) ? Wkb : (w == 2) ? Wvb : Wob;
  }
  float4 f = reinterpret_cast<const float4*>(src)[j];
  ushort4 o;
  o.x = f2bfu(f.x); o.y = f2bfu(f.y); o.z = f2bfu(f.z); o.w = f2bfu(f.w);
  reinterpret_cast<ushort4*>(dst)[j] = o;
}

// ---- key_scores[t] = x[t,:]·Wks + bks  (fp32; one wave per row) ----
__global__ __launch_bounds__(256) void scores_kernel(
    const float* __restrict__ x, const float* __restrict__ Wks,
    const float* __restrict__ bks, float* __restrict__ scores) {
  const int t = blockIdx.x * 4 + (threadIdx.x >> 6);
  const int lane = threadIdx.x & 63;
  const float* xrow = x + (size_t)t * C_DIM;
  float acc = 0.f;
  #pragma unroll 4
  for (int i = lane; i < C_DIM; i += 64)
    acc += xrow[i] * Wks[i];
  #pragma unroll
  for (int o = 32; o; o >>= 1) acc += __shfl_xor(acc, o);
  if (lane == 0) scores[t] = acc + bks[0];
}

// ---- rank-by-counting sort: sorted[rank_i] = i ----
__global__ __launch_bounds__(256) void rank_sort_kernel(
    const float* __restrict__ scores, int* __restrict__ sorted_idx) {
  __shared__ float ss[T_DIM];
  const int tid = threadIdx.x;
  const int i = blockIdx.x * 256 + tid;
  for (int j = tid; j < T_DIM; j += 256) ss[j] = scores[j];
  __syncthreads();
  const float si = ss[i];
  int rank = 0;
  #pragma unroll 8
  for (int j = 0; j < T_DIM; ++j) {
    float sj = ss[j];
    rank += (int)((sj > si) || (sj == si && j < i));
  }
  sorted_idx[rank] = i;
}

// ---- per-t top-64 selection: one wave per t, ballot + prefix-popcount ----
__global__ __launch_bounds__(256) void select_topk_kernel(
    const int* __restrict__ sorted_idx, int* __restrict__ topk) {
  __shared__ int ss[T_DIM];
  const int tid = threadIdx.x;
  for (int i = tid; i < T_DIM; i += 256) {
    int s = sorted_idx[i];
    ss[i] = (s < 0) ? 0 : (s > T_DIM - 1 ? T_DIM - 1 : s);
  }
  __syncthreads();
  const int t = blockIdx.x * 4 + (tid >> 6);
  const int lane = tid & 63;
  if (t <= 63) {
    topk[(size_t)t * KSP + lane] = (lane < t) ? lane : t;
  } else {
    const unsigned long long lt_mask = (1ull << lane) - 1ull;
    int count = 0;
    for (int chunk = 0; chunk < T_DIM / 64 && count < KSP; ++chunk) {
      int s = ss[chunk * 64 + lane];
      bool ok = (s <= t);
      unsigned long long m = __ballot(ok);
      int pos = count + __popcll(m & lt_mask);
      if (ok && pos < KSP) topk[(size_t)t * KSP + pos] = s;
      count += __popcll(m);
    }
  }
}

// ---- GEMM body: 128x128 tile, BK=64; 4 waves, each 64x64 (4x4 accs) ----
__device__ __forceinline__ void gemm_body_128(
    const unsigned short* __restrict__ A, const unsigned short* __restrict__ W,
    f32x4 acc[4][4], int bm, int bn, int tid) {
  __shared__ unsigned short As[GBM][GPAD];  // 18 KB
  __shared__ unsigned short Ws[GBN][GPAD];  // 18 KB
  const int w = tid >> 6, lane = tid & 63;
  const int quad = lane >> 4, r = lane & 15;
  const int wm = (w >> 1) * 64, wn = (w & 1) * 64;
  const int s_row = tid >> 3;          // 0..31
  const int s_ke = (tid & 7) * 8;      // element offset 0..56
  const unsigned short* Abase = A + (size_t)(bm * GBM + s_row) * C_DIM + s_ke;
  const unsigned short* Wbase = W + (size_t)(bn * GBN + s_row) * C_DIM + s_ke;
  for (int kb = 0; kb < C_DIM; kb += GBK) {
    #pragma unroll
    for (int i = 0; i < 4; ++i)
      *reinterpret_cast<short8*>(&As[s_row + 32 * i][s_ke]) =
          *reinterpret_cast<const short8*>(Abase + kb + (size_t)(32 * i) * C_DIM);
    #pragma unroll
    for (int i = 0; i < 4; ++i)
      *reinterpret_cast<short8*>(&Ws[s_row + 32 * i][s_ke]) =
          *reinterpret_cast<const short8*>(Wbase + kb + (size_t)(32 * i) * C_DIM);
    __syncthreads();
    #pragma unroll
    for (int ks = 0; ks < 2; ++ks) {
      short8 af[4], bfr[4];
      #pragma unroll
      for (int mi = 0; mi < 4; ++mi)
        af[mi] = *reinterpret_cast<const short8*>(&As[wm + mi * 16 + r][ks * 32 + quad * 8]);
      #pragma unroll
      for (int ni = 0; ni < 4; ++ni)
        bfr[ni] = *reinterpret_cast<const short8*>(&Ws[wn + ni * 16 + r][ks * 32 + quad * 8]);
      #pragma unroll
      for (int mi = 0; mi < 4; ++mi)
        #pragma unroll
        for (int ni = 0; ni < 4; ++ni)
          acc[mi][ni] = __builtin_amdgcn_mfma_f32_16x16x32_bf16(af[mi], bfr[ni], acc[mi][ni], 0, 0, 0);
    }
    __syncthreads();
  }
}

// ---- fused QKV projection: q -> bf16, k -> bf16, v -> fp32 ----
__global__ __launch_bounds__(256) void gemm_qkv_kernel(
    const unsigned short* __restrict__ A,
    const unsigned short* __restrict__ Wq, const unsigned short* __restrict__ Wk,
    const unsigned short* __restrict__ Wv,
    const float* __restrict__ bq, const float* __restrict__ bk,
    const float* __restrict__ bv,
    unsigned short* __restrict__ qo, unsigned short* __restrict__ ko,
    float* __restrict__ vo) {
  const int per = (T_DIM / GBM) * (C_DIM / GBN);  // 128
  const int which = blockIdx.x / per;
  const int rem = blockIdx.x % per;
  const int bm = rem / (C_DIM / GBN);
  const int bn = rem % (C_DIM / GBN);
  const unsigned short* W = (which == 0) ? Wq : (which == 1) ? Wk : Wv;
  const float* bias = (which == 0) ? bq : (which == 1) ? bk : bv;
  const int tid = threadIdx.x;
  f32x4 acc[4][4] = {};
  gemm_body_128(A, W, acc, bm, bn, tid);
  const int w = tid >> 6, lane = tid & 63;
  const int quad = lane >> 4, r = lane & 15;
  const int wm = (w >> 1) * 64, wn = (w & 1) * 64;
  #pragma unroll
  for (int mi = 0; mi < 4; ++mi) {
    #pragma unroll
    for (int ni = 0; ni < 4; ++ni) {
      const int col = bn * GBN + wn + ni * 16 + r;
      const float bf = bias[col];
      #pragma unroll
      for (int i = 0; i < 4; ++i) {
        const int row = bm * GBM + wm + mi * 16 + quad * 4 + i;
        const float val = acc[mi][ni][i] + bf;
        if (which == 2) {
          vo[(size_t)row * C_DIM + col] = val;
        } else {
          unsigned short* o = (which == 0) ? qo : ko;
          o[(size_t)row * C_DIM + col] = f2bfu(val);
        }
      }
    }
  }
}

// ---- output projection GEMM, fp32 out ----
__global__ __launch_bounds__(256) void gemm_o_f32_kernel(
    const unsigned short* __restrict__ A, const unsigned short* __restrict__ W,
    const float* __restrict__ bias, float* __restrict__ out) {
  const int tid = threadIdx.x;
  const int bm = blockIdx.x / (C_DIM / GBN);
  const int bn = blockIdx.x % (C_DIM / GBN);
  f32x4 acc[4][4] = {};
  gemm_body_128(A, W, acc, bm, bn, tid);
  const int w = tid >> 6, lane = tid & 63;
  const int quad = lane >> 4, r = lane & 15;
  const int wm = (w >> 1) * 64, wn = (w & 1) * 64;
  #pragma unroll
  for (int mi = 0; mi < 4; ++mi) {
    #pragma unroll
    for (int ni = 0; ni < 4; ++ni) {
      const int col = bn * GBN + wn + ni * 16 + r;
      const float bf = bias[col];
      #pragma unroll
      for (int i = 0; i < 4; ++i) {
        const int row = bm * GBM + wm + mi * 16 + quad * 4 + i;
        out[(size_t)row * C_DIM + col] = acc[mi][ni][i] + bf;
      }
    }
  }
}

// ---- sparse attention v4: block per (t, head-group), one wave per head;
// K bf16, V fp32; (off,prob) packed into one float2 LDS slot ----
__global__ __launch_bounds__(256) void attn_kernel(
    const unsigned short* __restrict__ q, const unsigned short* __restrict__ k,
    const float* __restrict__ v, const int* __restrict__ topk,
    unsigned short* __restrict__ attn_out) {
  __shared__ float2 po_s[4][KSP];   // per-wave: {offset-bits, prob}
  __shared__ float q_s[4][HS];      // per-wave: q vector
  const int t = blockIdx.x >> 2;
  const int hg = blockIdx.x & 3;
  const int tid = threadIdx.x;
  const int w = tid >> 6, lane = tid & 63;
  const int h = hg * 4 + w;
  int s = topk[(size_t)t * KSP + lane];
  s = (s < 0) ? 0 : (s > t ? t : s);  // valid set is [0, t]
  const int my_off = s * C_DIM;
  q_s[w][lane] = bfu2f(q[(size_t)t * C_DIM + h * HS + lane]);
  __builtin_amdgcn_wave_barrier();
  // phase 1: lane j owns key j; 4 independent accumulators
  const unsigned short* krow = k + my_off + h * HS;
  float l0 = 0.f, l1 = 0.f, l2 = 0.f, l3 = 0.f;
  #pragma unroll
  for (int c8 = 0; c8 < 8; ++c8) {
    uint4 raw = *reinterpret_cast<const uint4*>(krow + c8 * 8);
    unsigned uu[4] = {raw.x, raw.y, raw.z, raw.w};
    l0 += q_s[w][c8 * 8 + 0] * __builtin_bit_cast(float, uu[0] << 16)
        + q_s[w][c8 * 8 + 1] * __builtin_bit_cast(float, uu[0] & 0xffff0000u);
    l1 += q_s[w][c8 * 8 + 2] * __builtin_bit_cast(float, uu[1] << 16)
        + q_s[w][c8 * 8 + 3] * __builtin_bit_cast(float, uu[1] & 0xffff0000u);
    l2 += q_s[w][c8 * 8 + 4] * __builtin_bit_cast(float, uu[2] << 16)
        + q_s[w][c8 * 8 + 5] * __builtin_bit_cast(float, uu[2] & 0xffff0000u);
    l3 += q_s[w][c8 * 8 + 6] * __builtin_bit_cast(float, uu[3] << 16)
        + q_s[w][c8 * 8 + 7] * __builtin_bit_cast(float, uu[3] & 0xffff0000u);
  }
  float lg = ((l0 + l1) + (l2 + l3)) * 0.125f;  // 1/sqrt(64)
  float m = lg;
  #pragma unroll
  for (int o = 32; o; o >>= 1) m = fmaxf(m, __shfl_xor(m, o));
  float pexp = __expf(lg - m);
  float sum = pexp;
  #pragma unroll
  for (int o = 32; o; o >>= 1) sum += __shfl_xor(sum, o);
  float2 po;
  po.x = __builtin_bit_cast(float, my_off);
  po.y = pexp / sum;
  po_s[w][lane] = po;
  __builtin_amdgcn_wave_barrier();
  // phase 2: lane owns channel `lane`; one b64 LDS read + one dword load per key
  const float* vbase = v + h * HS + lane;
  float a0 = 0.f, a1 = 0.f, a2 = 0.f, a3 = 0.f;
  #pragma unroll 4
  for (int j = 0; j < KSP; j += 4) {
    float2 p0 = po_s[w][j + 0];
    float2 p1 = po_s[w][j + 1];
    float2 p2 = po_s[w][j + 2];
    float2 p3 = po_s[w][j + 3];
    a0 += p0.y * vbase[__builtin_bit_cast(int, p0.x)];
    a1 += p1.y * vbase[__builtin_bit_cast(int, p1.x)];
    a2 += p2.y * vbase[__builtin_bit_cast(int, p2.x)];
    a3 += p3.y * vbase[__builtin_bit_cast(int, p3.x)];
  }
  attn_out[(size_t)t * C_DIM + h * HS + lane] = f2bfu((a0 + a1) + (a2 + a3));
}

extern "C" void kernel_launch(void* const* d_in, const int* in_sizes, int n_in,
                              void* d_out, int out_size, void* d_ws, size_t ws_size,
                              hipStream_t stream) {
  const float* x   = (const float*)d_in[0];
  const float* Wq  = (const float*)d_in[1];
  const float* bq  = (const float*)d_in[2];
  const float* Wk  = (const float*)d_in[3];
  const float* bk  = (const float*)d_in[4];
  const float* Wv  = (const float*)d_in[5];
  const float* bv  = (const float*)d_in[6];
  const float* Wo  = (const float*)d_in[7];
  const float* bo  = (const float*)d_in[8];
  const float* Wks = (const float*)d_in[9];
  const float* bks = (const float*)d_in[10];
  float* out = (float*)d_out;

  char* ws = (char*)d_ws;
  size_t off = 0;
  float* scores = (float*)(ws + off); off += 8192;
  int*   sorted = (int*)(ws + off);   off += 8192;
  int*   topk   = (int*)(ws + off);   off += (size_t)T_DIM * KSP * 4;
  unsigned short* xb  = (unsigned short*)(ws + off); off += (size_t)T_DIM * C_DIM * 2;
  unsigned short* Wqb = (unsigned short*)(ws + off); off += (size_t)C_DIM * C_DIM * 2;
  unsigned short* Wkb = (unsigned short*)(ws + off); off += (size_t)C_DIM * C_DIM * 2;
  unsigned short* Wvb = (unsigned short*)(ws + off); off += (size_t)C_DIM * C_DIM * 2;
  unsigned short* Wob = (unsigned short*)(ws + off); off += (size_t)C_DIM * C_DIM * 2;
  unsigned short* qb  = (unsigned short*)(ws + off); off += (size_t)T_DIM * C_DIM * 2;
  unsigned short* kb  = (unsigned short*)(ws + off); off += (size_t)T_DIM * C_DIM * 2;
  float*          vf  = (float*)(ws + off);          off += (size_t)T_DIM * C_DIM * 4;
  unsigned short* ab  = xb;  // alias: xb dead after gemm_qkv, ab written by attn

  const int n4_total = (T_DIM * C_DIM + 4 * C_DIM * C_DIM) / 4;
  convert_all_kernel<<<n4_total / 256, 256, 0, stream>>>(
      x, Wq, Wk, Wv, Wo, xb, Wqb, Wkb, Wvb, Wob);

  scores_kernel<<<T_DIM / 4, 256, 0, stream>>>(x, Wks, bks, scores);
  rank_sort_kernel<<<T_DIM / 256, 256, 0, stream>>>(scores, sorted);
  select_topk_kernel<<<T_DIM / 4, 256, 0, stream>>>(sorted, topk);

  // fused QKV projection: 3 x 128 blocks of 128x128
  gemm_qkv_kernel<<<3 * (T_DIM / GBM) * (C_DIM / GBN), 256, 0, stream>>>(
      xb, Wqb, Wkb, Wvb, bq, bk, bv, qb, kb, vf);

  // sparse attention: (t, head-group) grid
  attn_kernel<<<T_DIM * 4, 256, 0, stream>>>(qb, kb, vf, topk, ab);

  // output projection (fp32 out): 128 blocks of 128x128
  gemm_o_f32_kernel<<<(T_DIM / GBM) * (C_DIM / GBN), 256, 0, stream>>>(
      ab, Wob, bo, out);
}

// Round 9
// 236.379 us; speedup vs baseline: 1.0268x; 1.0268x over previous
//
#include <hip/hip_runtime.h>
#include <hip/hip_bf16.h>
#include <cstdint>
#include <cstddef>

#define T_DIM 2048
#define C_DIM 1024
#define NH 16
#define HS 64
#define KSP 64

// 128x64 GEMM tile, BK=64 (measured-best config, round 7)
#define GBM 128
#define GBN 64
#define GBK 64
#define GPAD 72  // 64+8 elems -> 144B row stride; frag reads 2-way alias (free)

typedef short short8 __attribute__((ext_vector_type(8)));
typedef float f32x4 __attribute__((ext_vector_type(4)));

__device__ __forceinline__ float bfu2f(unsigned short u) {
  unsigned v = ((unsigned)u) << 16;
  return __builtin_bit_cast(float, v);
}
__device__ __forceinline__ unsigned short f2bfu(float f) {
  unsigned u = __builtin_bit_cast(unsigned, f);
  unsigned r = (u + 0x7fffu + ((u >> 16) & 1u)) >> 16;
  return (unsigned short)r;
}

// ---- fused float32 -> bf16 conversion of x + 4 weight matrices ----
__global__ __launch_bounds__(256) void convert_all_kernel(
    const float* __restrict__ x, const float* __restrict__ Wq,
    const float* __restrict__ Wk, const float* __restrict__ Wv,
    const float* __restrict__ Wo,
    unsigned short* __restrict__ xb, unsigned short* __restrict__ Wqb,
    unsigned short* __restrict__ Wkb, unsigned short* __restrict__ Wvb,
    unsigned short* __restrict__ Wob) {
  const int i = blockIdx.x * 256 + threadIdx.x;
  const int NX4 = T_DIM * C_DIM / 4;
  const int NW4 = C_DIM * C_DIM / 4;
  const float* src;
  unsigned short* dst;
  int j = i;
  if (j < NX4) { src = x; dst = xb; }
  else {
    j -= NX4;
    int w = j / NW4;
    j -= w * NW4;
    src = (w == 0) ? Wq : (w == 1) ? Wk : (w == 2) ? Wv : Wo;
    dst = (w == 0) ? Wqb : (w == 1) ? Wkb : (w == 2) ? Wvb : Wob;
  }
  float4 f = reinterpret_cast<const float4*>(src)[j];
  ushort4 o;
  o.x = f2bfu(f.x); o.y = f2bfu(f.y); o.z = f2bfu(f.z); o.w = f2bfu(f.w);
  reinterpret_cast<ushort4*>(dst)[j] = o;
}

// ---- key_scores[t] = x[t,:]·Wks + bks  (fp32; one wave per row) ----
__global__ __launch_bounds__(256) void scores_kernel(
    const float* __restrict__ x, const float* __restrict__ Wks,
    const float* __restrict__ bks, float* __restrict__ scores) {
  const int t = blockIdx.x * 4 + (threadIdx.x >> 6);
  const int lane = threadIdx.x & 63;
  const float* xrow = x + (size_t)t * C_DIM;
  float acc = 0.f;
  #pragma unroll 4
  for (int i = lane; i < C_DIM; i += 64)
    acc += xrow[i] * Wks[i];
  #pragma unroll
  for (int o = 32; o; o >>= 1) acc += __shfl_xor(acc, o);
  if (lane == 0) scores[t] = acc + bks[0];
}

// ---- rank-by-counting sort: sorted[rank_i] = i ----
__global__ __launch_bounds__(256) void rank_sort_kernel(
    const float* __restrict__ scores, int* __restrict__ sorted_idx) {
  __shared__ float ss[T_DIM];
  const int tid = threadIdx.x;
  const int i = blockIdx.x * 256 + tid;
  for (int j = tid; j < T_DIM; j += 256) ss[j] = scores[j];
  __syncthreads();
  const float si = ss[i];
  int rank = 0;
  #pragma unroll 8
  for (int j = 0; j < T_DIM; ++j) {
    float sj = ss[j];
    rank += (int)((sj > si) || (sj == si && j < i));
  }
  sorted_idx[rank] = i;
}

// ---- per-t top-64 selection: one wave per t, ballot + prefix-popcount ----
__global__ __launch_bounds__(256) void select_topk_kernel(
    const int* __restrict__ sorted_idx, int* __restrict__ topk) {
  __shared__ int ss[T_DIM];
  const int tid = threadIdx.x;
  for (int i = tid; i < T_DIM; i += 256) {
    int s = sorted_idx[i];
    ss[i] = (s < 0) ? 0 : (s > T_DIM - 1 ? T_DIM - 1 : s);
  }
  __syncthreads();
  const int t = blockIdx.x * 4 + (tid >> 6);
  const int lane = tid & 63;
  if (t <= 63) {
    topk[(size_t)t * KSP + lane] = (lane < t) ? lane : t;
  } else {
    const unsigned long long lt_mask = (1ull << lane) - 1ull;
    int count = 0;
    for (int chunk = 0; chunk < T_DIM / 64 && count < KSP; ++chunk) {
      int s = ss[chunk * 64 + lane];
      bool ok = (s <= t);
      unsigned long long m = __ballot(ok);
      int pos = count + __popcll(m & lt_mask);
      if (ok && pos < KSP) topk[(size_t)t * KSP + pos] = s;
      count += __popcll(m);
    }
  }
}

// ---- GEMM body: 128x64 tile, BK=64; 4 waves, each 64x32 (4x2 accs of 16x16) ----
__device__ __forceinline__ void gemm_body_128x64(
    const unsigned short* __restrict__ A, const unsigned short* __restrict__ W,
    f32x4 acc[4][2], int bm, int bn, int tid) {
  __shared__ unsigned short As[GBM][GPAD];  // 18 KB
  __shared__ unsigned short Ws[GBN][GPAD];  // 9 KB
  const int w = tid >> 6, lane = tid & 63;
  const int quad = lane >> 4, r = lane & 15;
  const int wm = (w >> 1) * 64, wn = (w & 1) * 32;
  const int s_row = tid >> 3;          // 0..31
  const int s_ke = (tid & 7) * 8;      // element offset 0..56
  const unsigned short* Abase = A + (size_t)(bm * GBM + s_row) * C_DIM + s_ke;
  const unsigned short* Wbase = W + (size_t)(bn * GBN + s_row) * C_DIM + s_ke;
  for (int kb = 0; kb < C_DIM; kb += GBK) {
    #pragma unroll
    for (int i = 0; i < 4; ++i)
      *reinterpret_cast<short8*>(&As[s_row + 32 * i][s_ke]) =
          *reinterpret_cast<const short8*>(Abase + kb + (size_t)(32 * i) * C_DIM);
    #pragma unroll
    for (int i = 0; i < 2; ++i)
      *reinterpret_cast<short8*>(&Ws[s_row + 32 * i][s_ke]) =
          *reinterpret_cast<const short8*>(Wbase + kb + (size_t)(32 * i) * C_DIM);
    __syncthreads();
    #pragma unroll
    for (int ks = 0; ks < 2; ++ks) {
      short8 af[4], bfr[2];
      #pragma unroll
      for (int mi = 0; mi < 4; ++mi)
        af[mi] = *reinterpret_cast<const short8*>(&As[wm + mi * 16 + r][ks * 32 + quad * 8]);
      #pragma unroll
      for (int ni = 0; ni < 2; ++ni)
        bfr[ni] = *reinterpret_cast<const short8*>(&Ws[wn + ni * 16 + r][ks * 32 + quad * 8]);
      #pragma unroll
      for (int mi = 0; mi < 4; ++mi)
        #pragma unroll
        for (int ni = 0; ni < 2; ++ni)
          acc[mi][ni] = __builtin_amdgcn_mfma_f32_16x16x32_bf16(af[mi], bfr[ni], acc[mi][ni], 0, 0, 0);
    }
    __syncthreads();
  }
}

// ---- fused QKV projection: 3 GEMMs in one launch, bf16 out ----
__global__ __launch_bounds__(256) void gemm_qkv_kernel(
    const unsigned short* __restrict__ A,
    const unsigned short* __restrict__ Wq, const unsigned short* __restrict__ Wk,
    const unsigned short* __restrict__ Wv,
    const float* __restrict__ bq, const float* __restrict__ bk,
    const float* __restrict__ bv,
    unsigned short* __restrict__ qo, unsigned short* __restrict__ ko,
    unsigned short* __restrict__ vo) {
  const int per = (T_DIM / GBM) * (C_DIM / GBN);  // 256
  const int which = blockIdx.x / per;
  const int rem = blockIdx.x % per;
  const int bm = rem / (C_DIM / GBN);
  const int bn = rem % (C_DIM / GBN);
  const unsigned short* W = (which == 0) ? Wq : (which == 1) ? Wk : Wv;
  const float* bias = (which == 0) ? bq : (which == 1) ? bk : bv;
  unsigned short* out = (which == 0) ? qo : (which == 1) ? ko : vo;
  const int tid = threadIdx.x;
  f32x4 acc[4][2] = {};
  gemm_body_128x64(A, W, acc, bm, bn, tid);
  const int w = tid >> 6, lane = tid & 63;
  const int quad = lane >> 4, r = lane & 15;
  const int wm = (w >> 1) * 64, wn = (w & 1) * 32;
  #pragma unroll
  for (int mi = 0; mi < 4; ++mi) {
    #pragma unroll
    for (int ni = 0; ni < 2; ++ni) {
      const int col = bn * GBN + wn + ni * 16 + r;
      const float bf = bias[col];
      #pragma unroll
      for (int i = 0; i < 4; ++i) {
        const int row = bm * GBM + wm + mi * 16 + quad * 4 + i;
        out[(size_t)row * C_DIM + col] = f2bfu(acc[mi][ni][i] + bf);
      }
    }
  }
}

// ---- output projection GEMM, fp32 out ----
__global__ __launch_bounds__(256) void gemm_o_f32_kernel(
    const unsigned short* __restrict__ A, const unsigned short* __restrict__ W,
    const float* __restrict__ bias, float* __restrict__ out) {
  const int tid = threadIdx.x;
  const int bm = blockIdx.x / (C_DIM / GBN);
  const int bn = blockIdx.x % (C_DIM / GBN);
  f32x4 acc[4][2] = {};
  gemm_body_128x64(A, W, acc, bm, bn, tid);
  const int w = tid >> 6, lane = tid & 63;
  const int quad = lane >> 4, r = lane & 15;
  const int wm = (w >> 1) * 64, wn = (w & 1) * 32;
  #pragma unroll
  for (int mi = 0; mi < 4; ++mi) {
    #pragma unroll
    for (int ni = 0; ni < 2; ++ni) {
      const int col = bn * GBN + wn + ni * 16 + r;
      const float bf = bias[col];
      #pragma unroll
      for (int i = 0; i < 4; ++i) {
        const int row = bm * GBM + wm + mi * 16 + quad * 4 + i;
        out[(size_t)row * C_DIM + col] = acc[mi][ni][i] + bf;
      }
    }
  }
}

// ---- sparse attention v5: block per (t, head-group), one wave per head.
// Phase 2 packs 4 bf16 channels per b64 load: lane = (ksub<<4)|c4,
// c4 owns channels 4c4..4c4+3, ksub covers keys ksub::4 (16 iters),
// then shfl_xor(16,32) cross-key reduction; lanes<16 store ushort4. ----
__global__ __launch_bounds__(256) void attn_kernel(
    const unsigned short* __restrict__ q, const unsigned short* __restrict__ k,
    const unsigned short* __restrict__ v, const int* __restrict__ topk,
    unsigned short* __restrict__ attn_out) {
  __shared__ float2 po_s[4][KSP];   // per-wave: {offset-bits, prob}
  __shared__ float q_s[4][HS];      // per-wave: q vector
  const int t = blockIdx.x >> 2;
  const int hg = blockIdx.x & 3;
  const int tid = threadIdx.x;
  const int w = tid >> 6, lane = tid & 63;
  const int h = hg * 4 + w;
  int s = topk[(size_t)t * KSP + lane];
  s = (s < 0) ? 0 : (s > t ? t : s);  // valid set is [0, t]
  const int my_off = s * C_DIM;
  q_s[w][lane] = bfu2f(q[(size_t)t * C_DIM + h * HS + lane]);
  __builtin_amdgcn_wave_barrier();
  // phase 1: lane j owns key j; 4 independent accumulators; float4 q reads
  const unsigned short* krow = k + my_off + h * HS;
  float l0 = 0.f, l1 = 0.f, l2 = 0.f, l3 = 0.f;
  #pragma unroll
  for (int c8 = 0; c8 < 8; ++c8) {
    uint4 raw = *reinterpret_cast<const uint4*>(krow + c8 * 8);
    float4 q0 = *reinterpret_cast<const float4*>(&q_s[w][c8 * 8]);
    float4 q1 = *reinterpret_cast<const float4*>(&q_s[w][c8 * 8 + 4]);
    l0 += q0.x * __builtin_bit_cast(float, raw.x << 16)
        + q0.y * __builtin_bit_cast(float, raw.x & 0xffff0000u);
    l1 += q0.z * __builtin_bit_cast(float, raw.y << 16)
        + q0.w * __builtin_bit_cast(float, raw.y & 0xffff0000u);
    l2 += q1.x * __builtin_bit_cast(float, raw.z << 16)
        + q1.y * __builtin_bit_cast(float, raw.z & 0xffff0000u);
    l3 += q1.z * __builtin_bit_cast(float, raw.w << 16)
        + q1.w * __builtin_bit_cast(float, raw.w & 0xffff0000u);
  }
  float lg = ((l0 + l1) + (l2 + l3)) * 0.125f;  // 1/sqrt(64)
  float m = lg;
  #pragma unroll
  for (int o = 32; o; o >>= 1) m = fmaxf(m, __shfl_xor(m, o));
  float pexp = __expf(lg - m);
  float sum = pexp;
  #pragma unroll
  for (int o = 32; o; o >>= 1) sum += __shfl_xor(sum, o);
  float2 po;
  po.x = __builtin_bit_cast(float, my_off);
  po.y = pexp / sum;
  po_s[w][lane] = po;
  __builtin_amdgcn_wave_barrier();
  // phase 2: 16 b64 loads per lane (4 channels each)
  const int c4 = lane & 15;     // channel quad: channels 4*c4 .. 4*c4+3
  const int ksub = lane >> 4;   // key subset: keys ksub, ksub+4, ...
  const unsigned short* vch = v + h * HS + 4 * c4;
  float a0 = 0.f, a1 = 0.f, a2 = 0.f, a3 = 0.f;
  #pragma unroll 8
  for (int jj = 0; jj < 16; ++jj) {
    const int j = 4 * jj + ksub;
    float2 po2 = po_s[w][j];
    const float p = po2.y;
    uint2 raw = *reinterpret_cast<const uint2*>(vch + __builtin_bit_cast(int, po2.x));
    a0 += p * __builtin_bit_cast(float, raw.x << 16);
    a1 += p * __builtin_bit_cast(float, raw.x & 0xffff0000u);
    a2 += p * __builtin_bit_cast(float, raw.y << 16);
    a3 += p * __builtin_bit_cast(float, raw.y & 0xffff0000u);
  }
  // reduce across the 4 key subsets (lanes c4, c4+16, c4+32, c4+48)
  #pragma unroll
  for (int o = 16; o <= 32; o <<= 1) {
    a0 += __shfl_xor(a0, o);
    a1 += __shfl_xor(a1, o);
    a2 += __shfl_xor(a2, o);
    a3 += __shfl_xor(a3, o);
  }
  if (lane < 16) {
    ushort4 ov;
    ov.x = f2bfu(a0); ov.y = f2bfu(a1); ov.z = f2bfu(a2); ov.w = f2bfu(a3);
    *reinterpret_cast<ushort4*>(attn_out + (size_t)t * C_DIM + h * HS + 4 * c4) = ov;
  }
}

extern "C" void kernel_launch(void* const* d_in, const int* in_sizes, int n_in,
                              void* d_out, int out_size, void* d_ws, size_t ws_size,
                              hipStream_t stream) {
  const float* x   = (const float*)d_in[0];
  const float* Wq  = (const float*)d_in[1];
  const float* bq  = (const float*)d_in[2];
  const float* Wk  = (const float*)d_in[3];
  const float* bk  = (const float*)d_in[4];
  const float* Wv  = (const float*)d_in[5];
  const float* bv  = (const float*)d_in[6];
  const float* Wo  = (const float*)d_in[7];
  const float* bo  = (const float*)d_in[8];
  const float* Wks = (const float*)d_in[9];
  const float* bks = (const float*)d_in[10];
  float* out = (float*)d_out;

  char* ws = (char*)d_ws;
  size_t off = 0;
  float* scores = (float*)(ws + off); off += 8192;
  int*   sorted = (int*)(ws + off);   off += 8192;
  int*   topk   = (int*)(ws + off);   off += (size_t)T_DIM * KSP * 4;
  unsigned short* xb  = (unsigned short*)(ws + off); off += (size_t)T_DIM * C_DIM * 2;
  unsigned short* Wqb = (unsigned short*)(ws + off); off += (size_t)C_DIM * C_DIM * 2;
  unsigned short* Wkb = (unsigned short*)(ws + off); off += (size_t)C_DIM * C_DIM * 2;
  unsigned short* Wvb = (unsigned short*)(ws + off); off += (size_t)C_DIM * C_DIM * 2;
  unsigned short* Wob = (unsigned short*)(ws + off); off += (size_t)C_DIM * C_DIM * 2;
  unsigned short* qb  = (unsigned short*)(ws + off); off += (size_t)T_DIM * C_DIM * 2;
  unsigned short* kb  = (unsigned short*)(ws + off); off += (size_t)T_DIM * C_DIM * 2;
  unsigned short* vb  = (unsigned short*)(ws + off); off += (size_t)T_DIM * C_DIM * 2;
  unsigned short* ab  = xb;  // alias: xb dead after gemm_qkv, ab written by attn

  const int n4_total = (T_DIM * C_DIM + 4 * C_DIM * C_DIM) / 4;
  convert_all_kernel<<<n4_total / 256, 256, 0, stream>>>(
      x, Wq, Wk, Wv, Wo, xb, Wqb, Wkb, Wvb, Wob);

  scores_kernel<<<T_DIM / 4, 256, 0, stream>>>(x, Wks, bks, scores);
  rank_sort_kernel<<<T_DIM / 256, 256, 0, stream>>>(scores, sorted);
  select_topk_kernel<<<T_DIM / 4, 256, 0, stream>>>(sorted, topk);

  // fused QKV projection: 3 x 256 blocks of 128x64
  gemm_qkv_kernel<<<3 * (T_DIM / GBM) * (C_DIM / GBN), 256, 0, stream>>>(
      xb, Wqb, Wkb, Wvb, bq, bk, bv, qb, kb, vb);

  // sparse attention: (t, head-group) grid
  attn_kernel<<<T_DIM * 4, 256, 0, stream>>>(qb, kb, vb, topk, ab);

  // output projection (fp32 out): 256 blocks of 128x64
  gemm_o_f32_kernel<<<(T_DIM / GBM) * (C_DIM / GBN), 256, 0, stream>>>(
      ab, Wob, bo, out);
}

// Round 10
// 227.245 us; speedup vs baseline: 1.0681x; 1.0402x over previous
//
#include <hip/hip_runtime.h>
#include <hip/hip_bf16.h>
#include <cstdint>
#include <cstddef>

#define T_DIM 2048
#define C_DIM 1024
#define NH 16
#define HS 64
#define KSP 64

// 128x64 GEMM tile, BK=64
#define GBM 128
#define GBN 64
#define GBK 64
#define GPAD 72

typedef short short8 __attribute__((ext_vector_type(8)));
typedef float f32x4 __attribute__((ext_vector_type(4)));

__device__ __forceinline__ float bfu2f(unsigned short u) {
  unsigned v = ((unsigned)u) << 16;
  return __builtin_bit_cast(float, v);
}
__device__ __forceinline__ unsigned short f2bfu(float f) {
  unsigned u = __builtin_bit_cast(unsigned, f);
  unsigned r = (u + 0x7fffu + ((u >> 16) & 1u)) >> 16;
  return (unsigned short)r;
}
__device__ __forceinline__ float bflo(unsigned u) {
  return __builtin_bit_cast(float, u << 16);
}
__device__ __forceinline__ float bfhi(unsigned u) {
  return __builtin_bit_cast(float, u & 0xffff0000u);
}

// ---- fused float32 -> bf16 conversion of x + 4 weight matrices ----
__global__ __launch_bounds__(256) void convert_all_kernel(
    const float* __restrict__ x, const float* __restrict__ Wq,
    const float* __restrict__ Wk, const float* __restrict__ Wv,
    const float* __restrict__ Wo,
    unsigned short* __restrict__ xb, unsigned short* __restrict__ Wqb,
    unsigned short* __restrict__ Wkb, unsigned short* __restrict__ Wvb,
    unsigned short* __restrict__ Wob) {
  const int i = blockIdx.x * 256 + threadIdx.x;
  const int NX4 = T_DIM * C_DIM / 4;
  const int NW4 = C_DIM * C_DIM / 4;
  const float* src;
  unsigned short* dst;
  int j = i;
  if (j < NX4) { src = x; dst = xb; }
  else {
    j -= NX4;
    int w = j / NW4;
    j -= w * NW4;
    src = (w == 0) ? Wq : (w == 1) ? Wk : (w == 2) ? Wv : Wo;
    dst = (w == 0) ? Wqb : (w == 1) ? Wkb : (w == 2) ? Wvb : Wob;
  }
  float4 f = reinterpret_cast<const float4*>(src)[j];
  ushort4 o;
  o.x = f2bfu(f.x); o.y = f2bfu(f.y); o.z = f2bfu(f.z); o.w = f2bfu(f.w);
  reinterpret_cast<ushort4*>(dst)[j] = o;
}

// ---- key_scores[t] = x[t,:]·Wks + bks  (fp32; one wave per row) ----
__global__ __launch_bounds__(256) void scores_kernel(
    const float* __restrict__ x, const float* __restrict__ Wks,
    const float* __restrict__ bks, float* __restrict__ scores) {
  const int t = blockIdx.x * 4 + (threadIdx.x >> 6);
  const int lane = threadIdx.x & 63;
  const float* xrow = x + (size_t)t * C_DIM;
  float acc = 0.f;
  #pragma unroll 4
  for (int i = lane; i < C_DIM; i += 64)
    acc += xrow[i] * Wks[i];
  #pragma unroll
  for (int o = 32; o; o >>= 1) acc += __shfl_xor(acc, o);
  if (lane == 0) scores[t] = acc + bks[0];
}

// ---- rank-by-counting sort: sorted[rank_i] = i ----
__global__ __launch_bounds__(256) void rank_sort_kernel(
    const float* __restrict__ scores, int* __restrict__ sorted_idx) {
  __shared__ float ss[T_DIM];
  const int tid = threadIdx.x;
  const int i = blockIdx.x * 256 + tid;
  for (int j = tid; j < T_DIM; j += 256) ss[j] = scores[j];
  __syncthreads();
  const float si = ss[i];
  int rank = 0;
  #pragma unroll 8
  for (int j = 0; j < T_DIM; ++j) {
    float sj = ss[j];
    rank += (int)((sj > si) || (sj == si && j < i));
  }
  sorted_idx[rank] = i;
}

// ---- per-t top-64 selection: one wave per t, ballot + prefix-popcount ----
__global__ __launch_bounds__(256) void select_topk_kernel(
    const int* __restrict__ sorted_idx, int* __restrict__ topk) {
  __shared__ int ss[T_DIM];
  const int tid = threadIdx.x;
  for (int i = tid; i < T_DIM; i += 256) {
    int s = sorted_idx[i];
    ss[i] = (s < 0) ? 0 : (s > T_DIM - 1 ? T_DIM - 1 : s);
  }
  __syncthreads();
  const int t = blockIdx.x * 4 + (tid >> 6);
  const int lane = tid & 63;
  if (t <= 63) {
    topk[(size_t)t * KSP + lane] = (lane < t) ? lane : t;
  } else {
    const unsigned long long lt_mask = (1ull << lane) - 1ull;
    int count = 0;
    for (int chunk = 0; chunk < T_DIM / 64 && count < KSP; ++chunk) {
      int s = ss[chunk * 64 + lane];
      bool ok = (s <= t);
      unsigned long long m = __ballot(ok);
      int pos = count + __popcll(m & lt_mask);
      if (ok && pos < KSP) topk[(size_t)t * KSP + pos] = s;
      count += __popcll(m);
    }
  }
}

// ---- GEMM body: 128x64 tile, BK=64; 4 waves, each 64x32 (4x2 accs) ----
__device__ __forceinline__ void gemm_body_128x64(
    const unsigned short* __restrict__ A, const unsigned short* __restrict__ W,
    f32x4 acc[4][2], int bm, int bn, int tid) {
  __shared__ unsigned short As[GBM][GPAD];
  __shared__ unsigned short Ws[GBN][GPAD];
  const int w = tid >> 6, lane = tid & 63;
  const int quad = lane >> 4, r = lane & 15;
  const int wm = (w >> 1) * 64, wn = (w & 1) * 32;
  const int s_row = tid >> 3;
  const int s_ke = (tid & 7) * 8;
  const unsigned short* Abase = A + (size_t)(bm * GBM + s_row) * C_DIM + s_ke;
  const unsigned short* Wbase = W + (size_t)(bn * GBN + s_row) * C_DIM + s_ke;
  for (int kb = 0; kb < C_DIM; kb += GBK) {
    #pragma unroll
    for (int i = 0; i < 4; ++i)
      *reinterpret_cast<short8*>(&As[s_row + 32 * i][s_ke]) =
          *reinterpret_cast<const short8*>(Abase + kb + (size_t)(32 * i) * C_DIM);
    #pragma unroll
    for (int i = 0; i < 2; ++i)
      *reinterpret_cast<short8*>(&Ws[s_row + 32 * i][s_ke]) =
          *reinterpret_cast<const short8*>(Wbase + kb + (size_t)(32 * i) * C_DIM);
    __syncthreads();
    #pragma unroll
    for (int ks = 0; ks < 2; ++ks) {
      short8 af[4], bfr[2];
      #pragma unroll
      for (int mi = 0; mi < 4; ++mi)
        af[mi] = *reinterpret_cast<const short8*>(&As[wm + mi * 16 + r][ks * 32 + quad * 8]);
      #pragma unroll
      for (int ni = 0; ni < 2; ++ni)
        bfr[ni] = *reinterpret_cast<const short8*>(&Ws[wn + ni * 16 + r][ks * 32 + quad * 8]);
      #pragma unroll
      for (int mi = 0; mi < 4; ++mi)
        #pragma unroll
        for (int ni = 0; ni < 2; ++ni)
          acc[mi][ni] = __builtin_amdgcn_mfma_f32_16x16x32_bf16(af[mi], bfr[ni], acc[mi][ni], 0, 0, 0);
    }
    __syncthreads();
  }
}

// ---- fused QKV projection: 3 GEMMs in one launch, bf16 out ----
__global__ __launch_bounds__(256) void gemm_qkv_kernel(
    const unsigned short* __restrict__ A,
    const unsigned short* __restrict__ Wq, const unsigned short* __restrict__ Wk,
    const unsigned short* __restrict__ Wv,
    const float* __restrict__ bq, const float* __restrict__ bk,
    const float* __restrict__ bv,
    unsigned short* __restrict__ qo, unsigned short* __restrict__ ko,
    unsigned short* __restrict__ vo) {
  const int per = (T_DIM / GBM) * (C_DIM / GBN);  // 256
  const int which = blockIdx.x / per;
  const int rem = blockIdx.x % per;
  const int bm = rem / (C_DIM / GBN);
  const int bn = rem % (C_DIM / GBN);
  const unsigned short* W = (which == 0) ? Wq : (which == 1) ? Wk : Wv;
  const float* bias = (which == 0) ? bq : (which == 1) ? bk : bv;
  unsigned short* out = (which == 0) ? qo : (which == 1) ? ko : vo;
  const int tid = threadIdx.x;
  f32x4 acc[4][2] = {};
  gemm_body_128x64(A, W, acc, bm, bn, tid);
  const int w = tid >> 6, lane = tid & 63;
  const int quad = lane >> 4, r = lane & 15;
  const int wm = (w >> 1) * 64, wn = (w & 1) * 32;
  #pragma unroll
  for (int mi = 0; mi < 4; ++mi) {
    #pragma unroll
    for (int ni = 0; ni < 2; ++ni) {
      const int col = bn * GBN + wn + ni * 16 + r;
      const float bf = bias[col];
      #pragma unroll
      for (int i = 0; i < 4; ++i) {
        const int row = bm * GBM + wm + mi * 16 + quad * 4 + i;
        out[(size_t)row * C_DIM + col] = f2bfu(acc[mi][ni][i] + bf);
      }
    }
  }
}

// ---- output projection GEMM, fp32 out ----
__global__ __launch_bounds__(256) void gemm_o_f32_kernel(
    const unsigned short* __restrict__ A, const unsigned short* __restrict__ W,
    const float* __restrict__ bias, float* __restrict__ out) {
  const int tid = threadIdx.x;
  const int bm = blockIdx.x / (C_DIM / GBN);
  const int bn = blockIdx.x % (C_DIM / GBN);
  f32x4 acc[4][2] = {};
  gemm_body_128x64(A, W, acc, bm, bn, tid);
  const int w = tid >> 6, lane = tid & 63;
  const int quad = lane >> 4, r = lane & 15;
  const int wm = (w >> 1) * 64, wn = (w & 1) * 32;
  #pragma unroll
  for (int mi = 0; mi < 4; ++mi) {
    #pragma unroll
    for (int ni = 0; ni < 2; ++ni) {
      const int col = bn * GBN + wn + ni * 16 + r;
      const float bf = bias[col];
      #pragma unroll
      for (int i = 0; i < 4; ++i) {
        const int row = bm * GBM + wm + mi * 16 + quad * 4 + i;
        out[(size_t)row * C_DIM + col] = acc[mi][ni][i] + bf;
      }
    }
  }
}

// ---- sparse attention v6: block per (t, head-group), one wave per head.
// Lane = (ksub=lane>>4, c4=lane&15). Both phases: the 16 lanes of a ksub
// group read ONE 128B line (4 bf16 channels each) of key row j=4*jj+ksub.
// Phase-1 partial dot is reduced across the group with 4 shfl_xor, which
// also broadcasts the logit to every lane that needs it in phase 2.
// K transactions/wave: ~512 -> ~64. Zero LDS in the hot loops. ----
__global__ __launch_bounds__(256) void attn_kernel(
    const unsigned short* __restrict__ q, const unsigned short* __restrict__ k,
    const unsigned short* __restrict__ v, const int* __restrict__ topk,
    unsigned short* __restrict__ attn_out) {
  __shared__ int off_s[4][KSP];
  const int t = blockIdx.x >> 2;
  const int hg = blockIdx.x & 3;
  const int tid = threadIdx.x;
  const int w = tid >> 6, lane = tid & 63;
  const int h = hg * 4 + w;
  const int c4 = lane & 15;     // channel quad: channels 4*c4 .. 4*c4+3
  const int ksub = lane >> 4;   // key subset
  {
    int s = topk[(size_t)t * KSP + lane];
    s = (s < 0) ? 0 : (s > t ? t : s);  // valid set is [0, t]
    off_s[w][lane] = s * C_DIM;
  }
  // q channels 4*c4..4*c4+3, pre-scaled by 1/sqrt(64)=0.125 (exact, pow2)
  float4 q4;
  {
    uint2 qraw = *reinterpret_cast<const uint2*>(
        q + (size_t)t * C_DIM + h * HS + 4 * c4);
    q4.x = 0.125f * bflo(qraw.x);
    q4.y = 0.125f * bfhi(qraw.x);
    q4.z = 0.125f * bflo(qraw.y);
    q4.w = 0.125f * bfhi(qraw.y);
  }
  __builtin_amdgcn_wave_barrier();
  const int hbase = h * HS + 4 * c4;
  // phase 1: 16 steps; step jj covers keys 4*jj + ksub
  float l[16];
  int offr[16];
  #pragma unroll
  for (int jj = 0; jj < 16; ++jj) {
    const int offj = off_s[w][4 * jj + ksub];
    offr[jj] = offj;
    uint2 raw = *reinterpret_cast<const uint2*>(k + offj + hbase);
    float pl = q4.x * bflo(raw.x) + q4.y * bfhi(raw.x)
             + q4.z * bflo(raw.y) + q4.w * bfhi(raw.y);
    pl += __shfl_xor(pl, 1);
    pl += __shfl_xor(pl, 2);
    pl += __shfl_xor(pl, 4);
    pl += __shfl_xor(pl, 8);
    l[jj] = pl;  // logit of key 4*jj+ksub, broadcast in group
  }
  // softmax over 64 keys: local 16 + cross-ksub (xor 16, 32)
  float m = l[0];
  #pragma unroll
  for (int jj = 1; jj < 16; ++jj) m = fmaxf(m, l[jj]);
  m = fmaxf(m, __shfl_xor(m, 16));
  m = fmaxf(m, __shfl_xor(m, 32));
  float sum = 0.f;
  #pragma unroll
  for (int jj = 0; jj < 16; ++jj) {
    l[jj] = __expf(l[jj] - m);
    sum += l[jj];
  }
  sum += __shfl_xor(sum, 16);
  sum += __shfl_xor(sum, 32);
  const float rs = 1.0f / sum;
  // phase 2: same access pattern on V; probs already in registers
  float a0 = 0.f, a1 = 0.f, a2 = 0.f, a3 = 0.f;
  #pragma unroll
  for (int jj = 0; jj < 16; ++jj) {
    uint2 raw = *reinterpret_cast<const uint2*>(v + offr[jj] + hbase);
    const float p = l[jj] * rs;
    a0 += p * bflo(raw.x);
    a1 += p * bfhi(raw.x);
    a2 += p * bflo(raw.y);
    a3 += p * bfhi(raw.y);
  }
  // reduce across the 4 key subsets
  #pragma unroll
  for (int o = 16; o <= 32; o <<= 1) {
    a0 += __shfl_xor(a0, o);
    a1 += __shfl_xor(a1, o);
    a2 += __shfl_xor(a2, o);
    a3 += __shfl_xor(a3, o);
  }
  if (ksub == 0) {
    ushort4 ov;
    ov.x = f2bfu(a0); ov.y = f2bfu(a1); ov.z = f2bfu(a2); ov.w = f2bfu(a3);
    *reinterpret_cast<ushort4*>(attn_out + (size_t)t * C_DIM + h * HS + 4 * c4) = ov;
  }
}

extern "C" void kernel_launch(void* const* d_in, const int* in_sizes, int n_in,
                              void* d_out, int out_size, void* d_ws, size_t ws_size,
                              hipStream_t stream) {
  const float* x   = (const float*)d_in[0];
  const float* Wq  = (const float*)d_in[1];
  const float* bq  = (const float*)d_in[2];
  const float* Wk  = (const float*)d_in[3];
  const float* bk  = (const float*)d_in[4];
  const float* Wv  = (const float*)d_in[5];
  const float* bv  = (const float*)d_in[6];
  const float* Wo  = (const float*)d_in[7];
  const float* bo  = (const float*)d_in[8];
  const float* Wks = (const float*)d_in[9];
  const float* bks = (const float*)d_in[10];
  float* out = (float*)d_out;

  char* ws = (char*)d_ws;
  size_t off = 0;
  float* scores = (float*)(ws + off); off += 8192;
  int*   sorted = (int*)(ws + off);   off += 8192;
  int*   topk   = (int*)(ws + off);   off += (size_t)T_DIM * KSP * 4;
  unsigned short* xb  = (unsigned short*)(ws + off); off += (size_t)T_DIM * C_DIM * 2;
  unsigned short* Wqb = (unsigned short*)(ws + off); off += (size_t)C_DIM * C_DIM * 2;
  unsigned short* Wkb = (unsigned short*)(ws + off); off += (size_t)C_DIM * C_DIM * 2;
  unsigned short* Wvb = (unsigned short*)(ws + off); off += (size_t)C_DIM * C_DIM * 2;
  unsigned short* Wob = (unsigned short*)(ws + off); off += (size_t)C_DIM * C_DIM * 2;
  unsigned short* qb  = (unsigned short*)(ws + off); off += (size_t)T_DIM * C_DIM * 2;
  unsigned short* kb  = (unsigned short*)(ws + off); off += (size_t)T_DIM * C_DIM * 2;
  unsigned short* vb  = (unsigned short*)(ws + off); off += (size_t)T_DIM * C_DIM * 2;
  unsigned short* ab  = xb;  // alias: xb dead after gemm_qkv

  const int n4_total = (T_DIM * C_DIM + 4 * C_DIM * C_DIM) / 4;
  convert_all_kernel<<<n4_total / 256, 256, 0, stream>>>(
      x, Wq, Wk, Wv, Wo, xb, Wqb, Wkb, Wvb, Wob);

  scores_kernel<<<T_DIM / 4, 256, 0, stream>>>(x, Wks, bks, scores);
  rank_sort_kernel<<<T_DIM / 256, 256, 0, stream>>>(scores, sorted);
  select_topk_kernel<<<T_DIM / 4, 256, 0, stream>>>(sorted, topk);

  gemm_qkv_kernel<<<3 * (T_DIM / GBM) * (C_DIM / GBN), 256, 0, stream>>>(
      xb, Wqb, Wkb, Wvb, bq, bk, bv, qb, kb, vb);

  attn_kernel<<<T_DIM * 4, 256, 0, stream>>>(qb, kb, vb, topk, ab);

  gemm_o_f32_kernel<<<(T_DIM / GBM) * (C_DIM / GBN), 256, 0, stream>>>(
      ab, Wob, bo, out);
}

// Round 11
// 178.289 us; speedup vs baseline: 1.3614x; 1.2746x over previous
//
#include <hip/hip_runtime.h>
#include <hip/hip_bf16.h>
#include <cstdint>
#include <cstddef>

#define T_DIM 2048
#define C_DIM 1024
#define NH 16
#define HS 64
#define KSP 64

// 128x64 GEMM tile, BK=64
#define GBM 128
#define GBN 64
#define GBK 64
#define GPAD 72

typedef short short8 __attribute__((ext_vector_type(8)));
typedef float f32x4 __attribute__((ext_vector_type(4)));

__device__ __forceinline__ float bfu2f(unsigned short u) {
  unsigned v = ((unsigned)u) << 16;
  return __builtin_bit_cast(float, v);
}
__device__ __forceinline__ unsigned short f2bfu(float f) {
  unsigned u = __builtin_bit_cast(unsigned, f);
  unsigned r = (u + 0x7fffu + ((u >> 16) & 1u)) >> 16;
  return (unsigned short)r;
}
__device__ __forceinline__ float bflo(unsigned u) {
  return __builtin_bit_cast(float, u << 16);
}
__device__ __forceinline__ float bfhi(unsigned u) {
  return __builtin_bit_cast(float, u & 0xffff0000u);
}

// ---- fused float32 -> bf16 conversion of x + 4 weight matrices ----
__global__ __launch_bounds__(256) void convert_all_kernel(
    const float* __restrict__ x, const float* __restrict__ Wq,
    const float* __restrict__ Wk, const float* __restrict__ Wv,
    const float* __restrict__ Wo,
    unsigned short* __restrict__ xb, unsigned short* __restrict__ Wqb,
    unsigned short* __restrict__ Wkb, unsigned short* __restrict__ Wvb,
    unsigned short* __restrict__ Wob) {
  const int i = blockIdx.x * 256 + threadIdx.x;
  const int NX4 = T_DIM * C_DIM / 4;
  const int NW4 = C_DIM * C_DIM / 4;
  const float* src;
  unsigned short* dst;
  int j = i;
  if (j < NX4) { src = x; dst = xb; }
  else {
    j -= NX4;
    int w = j / NW4;
    j -= w * NW4;
    src = (w == 0) ? Wq : (w == 1) ? Wk : (w == 2) ? Wv : Wo;
    dst = (w == 0) ? Wqb : (w == 1) ? Wkb : (w == 2) ? Wvb : Wob;
  }
  float4 f = reinterpret_cast<const float4*>(src)[j];
  ushort4 o;
  o.x = f2bfu(f.x); o.y = f2bfu(f.y); o.z = f2bfu(f.z); o.w = f2bfu(f.w);
  reinterpret_cast<ushort4*>(dst)[j] = o;
}

// ---- key_scores[t] = x[t,:]·Wks + bks  (fp32; one wave per row) ----
__global__ __launch_bounds__(256) void scores_kernel(
    const float* __restrict__ x, const float* __restrict__ Wks,
    const float* __restrict__ bks, float* __restrict__ scores) {
  const int t = blockIdx.x * 4 + (threadIdx.x >> 6);
  const int lane = threadIdx.x & 63;
  const float* xrow = x + (size_t)t * C_DIM;
  float acc = 0.f;
  #pragma unroll 4
  for (int i = lane; i < C_DIM; i += 64)
    acc += xrow[i] * Wks[i];
  #pragma unroll
  for (int o = 32; o; o >>= 1) acc += __shfl_xor(acc, o);
  if (lane == 0) scores[t] = acc + bks[0];
}

// ---- rank-by-counting sort v2: ONE WAVE PER ELEMENT, lane-parallel scan ----
__global__ __launch_bounds__(256) void rank_sort_kernel(
    const float* __restrict__ scores, int* __restrict__ sorted_idx) {
  __shared__ float ss[T_DIM];
  const int tid = threadIdx.x;
  for (int j = tid; j < T_DIM; j += 256) ss[j] = scores[j];
  __syncthreads();
  const int w = tid >> 6, lane = tid & 63;
  const int i = blockIdx.x * 4 + w;  // this wave's element
  const float si = ss[i];
  int rank = 0;
  #pragma unroll
  for (int step = 0; step < T_DIM / 64; ++step) {  // 32 independent LDS reads
    const int j = step * 64 + lane;
    const float sj = ss[j];
    rank += (int)((sj > si) || (sj == si && j < i));
  }
  #pragma unroll
  for (int o = 32; o; o >>= 1) rank += __shfl_xor(rank, o);
  if (lane == 0) sorted_idx[rank] = i;
}

// ---- per-t top-64 selection: one wave per t, ballot + prefix-popcount ----
__global__ __launch_bounds__(256) void select_topk_kernel(
    const int* __restrict__ sorted_idx, int* __restrict__ topk) {
  __shared__ int ss[T_DIM];
  const int tid = threadIdx.x;
  for (int i = tid; i < T_DIM; i += 256) {
    int s = sorted_idx[i];
    ss[i] = (s < 0) ? 0 : (s > T_DIM - 1 ? T_DIM - 1 : s);
  }
  __syncthreads();
  const int t = blockIdx.x * 4 + (tid >> 6);
  const int lane = tid & 63;
  if (t <= 63) {
    topk[(size_t)t * KSP + lane] = (lane < t) ? lane : t;
  } else {
    const unsigned long long lt_mask = (1ull << lane) - 1ull;
    int count = 0;
    for (int chunk = 0; chunk < T_DIM / 64 && count < KSP; ++chunk) {
      int s = ss[chunk * 64 + lane];
      bool ok = (s <= t);
      unsigned long long m = __ballot(ok);
      int pos = count + __popcll(m & lt_mask);
      if (ok && pos < KSP) topk[(size_t)t * KSP + pos] = s;
      count += __popcll(m);
    }
  }
}

// ---- GEMM body: 128x64 tile, BK=64; 4 waves, each 64x32 (4x2 accs) ----
__device__ __forceinline__ void gemm_body_128x64(
    const unsigned short* __restrict__ A, const unsigned short* __restrict__ W,
    f32x4 acc[4][2], int bm, int bn, int tid) {
  __shared__ unsigned short As[GBM][GPAD];
  __shared__ unsigned short Ws[GBN][GPAD];
  const int w = tid >> 6, lane = tid & 63;
  const int quad = lane >> 4, r = lane & 15;
  const int wm = (w >> 1) * 64, wn = (w & 1) * 32;
  const int s_row = tid >> 3;
  const int s_ke = (tid & 7) * 8;
  const unsigned short* Abase = A + (size_t)(bm * GBM + s_row) * C_DIM + s_ke;
  const unsigned short* Wbase = W + (size_t)(bn * GBN + s_row) * C_DIM + s_ke;
  for (int kb = 0; kb < C_DIM; kb += GBK) {
    #pragma unroll
    for (int i = 0; i < 4; ++i)
      *reinterpret_cast<short8*>(&As[s_row + 32 * i][s_ke]) =
          *reinterpret_cast<const short8*>(Abase + kb + (size_t)(32 * i) * C_DIM);
    #pragma unroll
    for (int i = 0; i < 2; ++i)
      *reinterpret_cast<short8*>(&Ws[s_row + 32 * i][s_ke]) =
          *reinterpret_cast<const short8*>(Wbase + kb + (size_t)(32 * i) * C_DIM);
    __syncthreads();
    #pragma unroll
    for (int ks = 0; ks < 2; ++ks) {
      short8 af[4], bfr[2];
      #pragma unroll
      for (int mi = 0; mi < 4; ++mi)
        af[mi] = *reinterpret_cast<const short8*>(&As[wm + mi * 16 + r][ks * 32 + quad * 8]);
      #pragma unroll
      for (int ni = 0; ni < 2; ++ni)
        bfr[ni] = *reinterpret_cast<const short8*>(&Ws[wn + ni * 16 + r][ks * 32 + quad * 8]);
      #pragma unroll
      for (int mi = 0; mi < 4; ++mi)
        #pragma unroll
        for (int ni = 0; ni < 2; ++ni)
          acc[mi][ni] = __builtin_amdgcn_mfma_f32_16x16x32_bf16(af[mi], bfr[ni], acc[mi][ni], 0, 0, 0);
    }
    __syncthreads();
  }
}

// ---- fused QKV projection: 3 GEMMs in one launch, bf16 out ----
__global__ __launch_bounds__(256) void gemm_qkv_kernel(
    const unsigned short* __restrict__ A,
    const unsigned short* __restrict__ Wq, const unsigned short* __restrict__ Wk,
    const unsigned short* __restrict__ Wv,
    const float* __restrict__ bq, const float* __restrict__ bk,
    const float* __restrict__ bv,
    unsigned short* __restrict__ qo, unsigned short* __restrict__ ko,
    unsigned short* __restrict__ vo) {
  const int per = (T_DIM / GBM) * (C_DIM / GBN);  // 256
  const int which = blockIdx.x / per;
  const int rem = blockIdx.x % per;
  const int bm = rem / (C_DIM / GBN);
  const int bn = rem % (C_DIM / GBN);
  const unsigned short* W = (which == 0) ? Wq : (which == 1) ? Wk : Wv;
  const float* bias = (which == 0) ? bq : (which == 1) ? bk : bv;
  unsigned short* out = (which == 0) ? qo : (which == 1) ? ko : vo;
  const int tid = threadIdx.x;
  f32x4 acc[4][2] = {};
  gemm_body_128x64(A, W, acc, bm, bn, tid);
  const int w = tid >> 6, lane = tid & 63;
  const int quad = lane >> 4, r = lane & 15;
  const int wm = (w >> 1) * 64, wn = (w & 1) * 32;
  #pragma unroll
  for (int mi = 0; mi < 4; ++mi) {
    #pragma unroll
    for (int ni = 0; ni < 2; ++ni) {
      const int col = bn * GBN + wn + ni * 16 + r;
      const float bf = bias[col];
      #pragma unroll
      for (int i = 0; i < 4; ++i) {
        const int row = bm * GBM + wm + mi * 16 + quad * 4 + i;
        out[(size_t)row * C_DIM + col] = f2bfu(acc[mi][ni][i] + bf);
      }
    }
  }
}

// ---- output projection GEMM, fp32 out ----
__global__ __launch_bounds__(256) void gemm_o_f32_kernel(
    const unsigned short* __restrict__ A, const unsigned short* __restrict__ W,
    const float* __restrict__ bias, float* __restrict__ out) {
  const int tid = threadIdx.x;
  const int bm = blockIdx.x / (C_DIM / GBN);
  const int bn = blockIdx.x % (C_DIM / GBN);
  f32x4 acc[4][2] = {};
  gemm_body_128x64(A, W, acc, bm, bn, tid);
  const int w = tid >> 6, lane = tid & 63;
  const int quad = lane >> 4, r = lane & 15;
  const int wm = (w >> 1) * 64, wn = (w & 1) * 32;
  #pragma unroll
  for (int mi = 0; mi < 4; ++mi) {
    #pragma unroll
    for (int ni = 0; ni < 2; ++ni) {
      const int col = bn * GBN + wn + ni * 16 + r;
      const float bf = bias[col];
      #pragma unroll
      for (int i = 0; i < 4; ++i) {
        const int row = bm * GBM + wm + mi * 16 + quad * 4 + i;
        out[(size_t)row * C_DIM + col] = acc[mi][ni][i] + bf;
      }
    }
  }
}

// ---- sparse attention v6: block per (t, head-group), one wave per head ----
__global__ __launch_bounds__(256) void attn_kernel(
    const unsigned short* __restrict__ q, const unsigned short* __restrict__ k,
    const unsigned short* __restrict__ v, const int* __restrict__ topk,
    unsigned short* __restrict__ attn_out) {
  __shared__ int off_s[4][KSP];
  const int t = blockIdx.x >> 2;
  const int hg = blockIdx.x & 3;
  const int tid = threadIdx.x;
  const int w = tid >> 6, lane = tid & 63;
  const int h = hg * 4 + w;
  const int c4 = lane & 15;     // channel quad: channels 4*c4 .. 4*c4+3
  const int ksub = lane >> 4;   // key subset
  {
    int s = topk[(size_t)t * KSP + lane];
    s = (s < 0) ? 0 : (s > t ? t : s);  // valid set is [0, t]
    off_s[w][lane] = s * C_DIM;
  }
  float4 q4;
  {
    uint2 qraw = *reinterpret_cast<const uint2*>(
        q + (size_t)t * C_DIM + h * HS + 4 * c4);
    q4.x = 0.125f * bflo(qraw.x);
    q4.y = 0.125f * bfhi(qraw.x);
    q4.z = 0.125f * bflo(qraw.y);
    q4.w = 0.125f * bfhi(qraw.y);
  }
  __builtin_amdgcn_wave_barrier();
  const int hbase = h * HS + 4 * c4;
  float l[16];
  int offr[16];
  #pragma unroll
  for (int jj = 0; jj < 16; ++jj) {
    const int offj = off_s[w][4 * jj + ksub];
    offr[jj] = offj;
    uint2 raw = *reinterpret_cast<const uint2*>(k + offj + hbase);
    float pl = q4.x * bflo(raw.x) + q4.y * bfhi(raw.x)
             + q4.z * bflo(raw.y) + q4.w * bfhi(raw.y);
    pl += __shfl_xor(pl, 1);
    pl += __shfl_xor(pl, 2);
    pl += __shfl_xor(pl, 4);
    pl += __shfl_xor(pl, 8);
    l[jj] = pl;
  }
  float m = l[0];
  #pragma unroll
  for (int jj = 1; jj < 16; ++jj) m = fmaxf(m, l[jj]);
  m = fmaxf(m, __shfl_xor(m, 16));
  m = fmaxf(m, __shfl_xor(m, 32));
  float sum = 0.f;
  #pragma unroll
  for (int jj = 0; jj < 16; ++jj) {
    l[jj] = __expf(l[jj] - m);
    sum += l[jj];
  }
  sum += __shfl_xor(sum, 16);
  sum += __shfl_xor(sum, 32);
  const float rs = 1.0f / sum;
  float a0 = 0.f, a1 = 0.f, a2 = 0.f, a3 = 0.f;
  #pragma unroll
  for (int jj = 0; jj < 16; ++jj) {
    uint2 raw = *reinterpret_cast<const uint2*>(v + offr[jj] + hbase);
    const float p = l[jj] * rs;
    a0 += p * bflo(raw.x);
    a1 += p * bfhi(raw.x);
    a2 += p * bflo(raw.y);
    a3 += p * bfhi(raw.y);
  }
  #pragma unroll
  for (int o = 16; o <= 32; o <<= 1) {
    a0 += __shfl_xor(a0, o);
    a1 += __shfl_xor(a1, o);
    a2 += __shfl_xor(a2, o);
    a3 += __shfl_xor(a3, o);
  }
  if (ksub == 0) {
    ushort4 ov;
    ov.x = f2bfu(a0); ov.y = f2bfu(a1); ov.z = f2bfu(a2); ov.w = f2bfu(a3);
    *reinterpret_cast<ushort4*>(attn_out + (size_t)t * C_DIM + h * HS + 4 * c4) = ov;
  }
}

extern "C" void kernel_launch(void* const* d_in, const int* in_sizes, int n_in,
                              void* d_out, int out_size, void* d_ws, size_t ws_size,
                              hipStream_t stream) {
  const float* x   = (const float*)d_in[0];
  const float* Wq  = (const float*)d_in[1];
  const float* bq  = (const float*)d_in[2];
  const float* Wk  = (const float*)d_in[3];
  const float* bk  = (const float*)d_in[4];
  const float* Wv  = (const float*)d_in[5];
  const float* bv  = (const float*)d_in[6];
  const float* Wo  = (const float*)d_in[7];
  const float* bo  = (const float*)d_in[8];
  const float* Wks = (const float*)d_in[9];
  const float* bks = (const float*)d_in[10];
  float* out = (float*)d_out;

  char* ws = (char*)d_ws;
  size_t off = 0;
  float* scores = (float*)(ws + off); off += 8192;
  int*   sorted = (int*)(ws + off);   off += 8192;
  int*   topk   = (int*)(ws + off);   off += (size_t)T_DIM * KSP * 4;
  unsigned short* xb  = (unsigned short*)(ws + off); off += (size_t)T_DIM * C_DIM * 2;
  unsigned short* Wqb = (unsigned short*)(ws + off); off += (size_t)C_DIM * C_DIM * 2;
  unsigned short* Wkb = (unsigned short*)(ws + off); off += (size_t)C_DIM * C_DIM * 2;
  unsigned short* Wvb = (unsigned short*)(ws + off); off += (size_t)C_DIM * C_DIM * 2;
  unsigned short* Wob = (unsigned short*)(ws + off); off += (size_t)C_DIM * C_DIM * 2;
  unsigned short* qb  = (unsigned short*)(ws + off); off += (size_t)T_DIM * C_DIM * 2;
  unsigned short* kb  = (unsigned short*)(ws + off); off += (size_t)T_DIM * C_DIM * 2;
  unsigned short* vb  = (unsigned short*)(ws + off); off += (size_t)T_DIM * C_DIM * 2;
  unsigned short* ab  = xb;  // alias: xb dead after gemm_qkv

  const int n4_total = (T_DIM * C_DIM + 4 * C_DIM * C_DIM) / 4;
  convert_all_kernel<<<n4_total / 256, 256, 0, stream>>>(
      x, Wq, Wk, Wv, Wo, xb, Wqb, Wkb, Wvb, Wob);

  scores_kernel<<<T_DIM / 4, 256, 0, stream>>>(x, Wks, bks, scores);
  rank_sort_kernel<<<T_DIM / 4, 256, 0, stream>>>(scores, sorted);
  select_topk_kernel<<<T_DIM / 4, 256, 0, stream>>>(sorted, topk);

  gemm_qkv_kernel<<<3 * (T_DIM / GBM) * (C_DIM / GBN), 256, 0, stream>>>(
      xb, Wqb, Wkb, Wvb, bq, bk, bv, qb, kb, vb);

  attn_kernel<<<T_DIM * 4, 256, 0, stream>>>(qb, kb, vb, topk, ab);

  gemm_o_f32_kernel<<<(T_DIM / GBM) * (C_DIM / GBN), 256, 0, stream>>>(
      ab, Wob, bo, out);
}

// Round 12
// 171.975 us; speedup vs baseline: 1.4114x; 1.0367x over previous
//
#include <hip/hip_runtime.h>
#include <hip/hip_bf16.h>
#include <cstdint>
#include <cstddef>

#define T_DIM 2048
#define C_DIM 1024
#define NH 16
#define HS 64
#define KSP 64

// 128x64 GEMM tile, BK=64, unpadded XOR-swizzled LDS (global_load_lds staging)
#define GBM 128
#define GBN 64
#define GBK 64

typedef short short8 __attribute__((ext_vector_type(8)));
typedef float f32x4 __attribute__((ext_vector_type(4)));

__device__ __forceinline__ float bfu2f(unsigned short u) {
  unsigned v = ((unsigned)u) << 16;
  return __builtin_bit_cast(float, v);
}
__device__ __forceinline__ unsigned short f2bfu(float f) {
  unsigned u = __builtin_bit_cast(unsigned, f);
  unsigned r = (u + 0x7fffu + ((u >> 16) & 1u)) >> 16;
  return (unsigned short)r;
}
__device__ __forceinline__ float bflo(unsigned u) {
  return __builtin_bit_cast(float, u << 16);
}
__device__ __forceinline__ float bfhi(unsigned u) {
  return __builtin_bit_cast(float, u & 0xffff0000u);
}

// async global->LDS, 16B per lane, dest = uniform base + lane*16
#define GLOAD_LDS16(gp, lp)                                                  \
  __builtin_amdgcn_global_load_lds(                                          \
      (const __attribute__((address_space(1))) void*)(gp),                   \
      (__attribute__((address_space(3))) void*)(lp), 16, 0, 0)

// ---- fused float32 -> bf16 conversion of x + 4 weight matrices ----
__global__ __launch_bounds__(256) void convert_all_kernel(
    const float* __restrict__ x, const float* __restrict__ Wq,
    const float* __restrict__ Wk, const float* __restrict__ Wv,
    const float* __restrict__ Wo,
    unsigned short* __restrict__ xb, unsigned short* __restrict__ Wqb,
    unsigned short* __restrict__ Wkb, unsigned short* __restrict__ Wvb,
    unsigned short* __restrict__ Wob) {
  const int i = blockIdx.x * 256 + threadIdx.x;
  const int NX4 = T_DIM * C_DIM / 4;
  const int NW4 = C_DIM * C_DIM / 4;
  const float* src;
  unsigned short* dst;
  int j = i;
  if (j < NX4) { src = x; dst = xb; }
  else {
    j -= NX4;
    int w = j / NW4;
    j -= w * NW4;
    src = (w == 0) ? Wq : (w == 1) ? Wk : (w == 2) ? Wv : Wo;
    dst = (w == 0) ? Wqb : (w == 1) ? Wkb : (w == 2) ? Wvb : Wob;
  }
  float4 f = reinterpret_cast<const float4*>(src)[j];
  ushort4 o;
  o.x = f2bfu(f.x); o.y = f2bfu(f.y); o.z = f2bfu(f.z); o.w = f2bfu(f.w);
  reinterpret_cast<ushort4*>(dst)[j] = o;
}

// ---- key_scores[t] = x[t,:]·Wks + bks  (fp32; one wave per row) ----
__global__ __launch_bounds__(256) void scores_kernel(
    const float* __restrict__ x, const float* __restrict__ Wks,
    const float* __restrict__ bks, float* __restrict__ scores) {
  const int t = blockIdx.x * 4 + (threadIdx.x >> 6);
  const int lane = threadIdx.x & 63;
  const float* xrow = x + (size_t)t * C_DIM;
  float acc = 0.f;
  #pragma unroll 4
  for (int i = lane; i < C_DIM; i += 64)
    acc += xrow[i] * Wks[i];
  #pragma unroll
  for (int o = 32; o; o >>= 1) acc += __shfl_xor(acc, o);
  if (lane == 0) scores[t] = acc + bks[0];
}

// ---- rank-by-counting sort: one wave per element, lane-parallel scan ----
__global__ __launch_bounds__(256) void rank_sort_kernel(
    const float* __restrict__ scores, int* __restrict__ sorted_idx) {
  __shared__ float ss[T_DIM];
  const int tid = threadIdx.x;
  for (int j = tid; j < T_DIM; j += 256) ss[j] = scores[j];
  __syncthreads();
  const int w = tid >> 6, lane = tid & 63;
  const int i = blockIdx.x * 4 + w;
  const float si = ss[i];
  int rank = 0;
  #pragma unroll
  for (int step = 0; step < T_DIM / 64; ++step) {
    const int j = step * 64 + lane;
    const float sj = ss[j];
    rank += (int)((sj > si) || (sj == si && j < i));
  }
  #pragma unroll
  for (int o = 32; o; o >>= 1) rank += __shfl_xor(rank, o);
  if (lane == 0) sorted_idx[rank] = i;
}

// ---- per-t top-64 selection: one wave per t, ballot + prefix-popcount ----
__global__ __launch_bounds__(256) void select_topk_kernel(
    const int* __restrict__ sorted_idx, int* __restrict__ topk) {
  __shared__ int ss[T_DIM];
  const int tid = threadIdx.x;
  for (int i = tid; i < T_DIM; i += 256) {
    int s = sorted_idx[i];
    ss[i] = (s < 0) ? 0 : (s > T_DIM - 1 ? T_DIM - 1 : s);
  }
  __syncthreads();
  const int t = blockIdx.x * 4 + (tid >> 6);
  const int lane = tid & 63;
  if (t <= 63) {
    topk[(size_t)t * KSP + lane] = (lane < t) ? lane : t;
  } else {
    const unsigned long long lt_mask = (1ull << lane) - 1ull;
    int count = 0;
    for (int chunk = 0; chunk < T_DIM / 64 && count < KSP; ++chunk) {
      int s = ss[chunk * 64 + lane];
      bool ok = (s <= t);
      unsigned long long m = __ballot(ok);
      int pos = count + __popcll(m & lt_mask);
      if (ok && pos < KSP) topk[(size_t)t * KSP + pos] = s;
      count += __popcll(m);
    }
  }
}

// ---- GEMM body: 128x64 tile, BK=64; global_load_lds staging, XOR swizzle.
// LDS layout: logical chunk q (8 bf16) of row rho at physical chunk q^(rho&7).
// Staging: lane l of wave w loads global chunk (l&7)^(row&7) of row base+(l>>3);
// dest = uniform row-block base + l*16B  ->  physical chunk l&7.  ----
__device__ __forceinline__ void gemm_body_128x64(
    const unsigned short* __restrict__ A, const unsigned short* __restrict__ W,
    f32x4 acc[4][2], int bm, int bn, int tid) {
  __shared__ unsigned short As[GBM * GBK];  // 16 KB
  __shared__ unsigned short Ws[GBN * GBK];  // 8 KB
  const int w = tid >> 6, lane = tid & 63;
  const int quad = lane >> 4, r = lane & 15;
  const int wm = (w >> 1) * 64, wn = (w & 1) * 32;
  const int sub = lane >> 3;       // 0..7 sub-row within 8-row chunk
  const int c = lane & 7;          // 0..7 chunk index
  const unsigned short* Arow[4];
  const unsigned short* Wrow[2];
  #pragma unroll
  for (int i = 0; i < 4; ++i) {
    const int row = w * 32 + i * 8 + sub;
    Arow[i] = A + (size_t)(bm * GBM + row) * C_DIM + ((c ^ (row & 7)) * 8);
  }
  #pragma unroll
  for (int i = 0; i < 2; ++i) {
    const int row = w * 16 + i * 8 + sub;
    Wrow[i] = W + (size_t)(bn * GBN + row) * C_DIM + ((c ^ (row & 7)) * 8);
  }
  for (int kb = 0; kb < C_DIM; kb += GBK) {
    #pragma unroll
    for (int i = 0; i < 4; ++i)
      GLOAD_LDS16(Arow[i] + kb, &As[(w * 32 + i * 8) * GBK]);
    #pragma unroll
    for (int i = 0; i < 2; ++i)
      GLOAD_LDS16(Wrow[i] + kb, &Ws[(w * 16 + i * 8) * GBK]);
    __syncthreads();
    #pragma unroll
    for (int ks = 0; ks < 2; ++ks) {
      const int pc = ((ks * 4 + quad) ^ (r & 7)) * 8;  // physical col offset
      short8 af[4], bfr[2];
      #pragma unroll
      for (int mi = 0; mi < 4; ++mi)
        af[mi] = *reinterpret_cast<const short8*>(&As[(wm + mi * 16 + r) * GBK + pc]);
      #pragma unroll
      for (int ni = 0; ni < 2; ++ni)
        bfr[ni] = *reinterpret_cast<const short8*>(&Ws[(wn + ni * 16 + r) * GBK + pc]);
      #pragma unroll
      for (int mi = 0; mi < 4; ++mi)
        #pragma unroll
        for (int ni = 0; ni < 2; ++ni)
          acc[mi][ni] = __builtin_amdgcn_mfma_f32_16x16x32_bf16(af[mi], bfr[ni], acc[mi][ni], 0, 0, 0);
    }
    __syncthreads();
  }
}

// ---- fused QKV projection: 3 GEMMs in one launch, bf16 out ----
__global__ __launch_bounds__(256) void gemm_qkv_kernel(
    const unsigned short* __restrict__ A,
    const unsigned short* __restrict__ Wq, const unsigned short* __restrict__ Wk,
    const unsigned short* __restrict__ Wv,
    const float* __restrict__ bq, const float* __restrict__ bk,
    const float* __restrict__ bv,
    unsigned short* __restrict__ qo, unsigned short* __restrict__ ko,
    unsigned short* __restrict__ vo) {
  const int per = (T_DIM / GBM) * (C_DIM / GBN);  // 256
  const int which = blockIdx.x / per;
  const int rem = blockIdx.x % per;
  const int bm = rem / (C_DIM / GBN);
  const int bn = rem % (C_DIM / GBN);
  const unsigned short* W = (which == 0) ? Wq : (which == 1) ? Wk : Wv;
  const float* bias = (which == 0) ? bq : (which == 1) ? bk : bv;
  unsigned short* out = (which == 0) ? qo : (which == 1) ? ko : vo;
  const int tid = threadIdx.x;
  f32x4 acc[4][2] = {};
  gemm_body_128x64(A, W, acc, bm, bn, tid);
  const int w = tid >> 6, lane = tid & 63;
  const int quad = lane >> 4, r = lane & 15;
  const int wm = (w >> 1) * 64, wn = (w & 1) * 32;
  #pragma unroll
  for (int mi = 0; mi < 4; ++mi) {
    #pragma unroll
    for (int ni = 0; ni < 2; ++ni) {
      const int col = bn * GBN + wn + ni * 16 + r;
      const float bf = bias[col];
      #pragma unroll
      for (int i = 0; i < 4; ++i) {
        const int row = bm * GBM + wm + mi * 16 + quad * 4 + i;
        out[(size_t)row * C_DIM + col] = f2bfu(acc[mi][ni][i] + bf);
      }
    }
  }
}

// ---- output projection GEMM, fp32 out ----
__global__ __launch_bounds__(256) void gemm_o_f32_kernel(
    const unsigned short* __restrict__ A, const unsigned short* __restrict__ W,
    const float* __restrict__ bias, float* __restrict__ out) {
  const int tid = threadIdx.x;
  const int bm = blockIdx.x / (C_DIM / GBN);
  const int bn = blockIdx.x % (C_DIM / GBN);
  f32x4 acc[4][2] = {};
  gemm_body_128x64(A, W, acc, bm, bn, tid);
  const int w = tid >> 6, lane = tid & 63;
  const int quad = lane >> 4, r = lane & 15;
  const int wm = (w >> 1) * 64, wn = (w & 1) * 32;
  #pragma unroll
  for (int mi = 0; mi < 4; ++mi) {
    #pragma unroll
    for (int ni = 0; ni < 2; ++ni) {
      const int col = bn * GBN + wn + ni * 16 + r;
      const float bf = bias[col];
      #pragma unroll
      for (int i = 0; i < 4; ++i) {
        const int row = bm * GBM + wm + mi * 16 + quad * 4 + i;
        out[(size_t)row * C_DIM + col] = acc[mi][ni][i] + bf;
      }
    }
  }
}

// ---- sparse attention v7: block per (t, head-group), one wave per head.
// Lane = (ksub=lane>>3, c8=lane&7): 8 lanes cover one key row with b128
// loads (8 bf16 channels each). 8 steps per phase. ----
__global__ __launch_bounds__(256) void attn_kernel(
    const unsigned short* __restrict__ q, const unsigned short* __restrict__ k,
    const unsigned short* __restrict__ v, const int* __restrict__ topk,
    unsigned short* __restrict__ attn_out) {
  __shared__ int off_s[4][KSP];
  const int t = blockIdx.x >> 2;
  const int hg = blockIdx.x & 3;
  const int tid = threadIdx.x;
  const int w = tid >> 6, lane = tid & 63;
  const int h = hg * 4 + w;
  const int c8 = lane & 7;     // channel octet: channels 8*c8 .. 8*c8+7
  const int ksub = lane >> 3;  // key subset: keys ksub, ksub+8, ...
  {
    int s = topk[(size_t)t * KSP + lane];
    s = (s < 0) ? 0 : (s > t ? t : s);  // valid set is [0, t]
    off_s[w][lane] = s * C_DIM;
  }
  const int hbase = h * HS + 8 * c8;
  // q channels, pre-scaled by 1/sqrt(64)=0.125 (exact pow2)
  float qv[8];
  {
    uint4 qraw = *reinterpret_cast<const uint4*>(q + (size_t)t * C_DIM + hbase);
    qv[0] = 0.125f * bflo(qraw.x); qv[1] = 0.125f * bfhi(qraw.x);
    qv[2] = 0.125f * bflo(qraw.y); qv[3] = 0.125f * bfhi(qraw.y);
    qv[4] = 0.125f * bflo(qraw.z); qv[5] = 0.125f * bfhi(qraw.z);
    qv[6] = 0.125f * bflo(qraw.w); qv[7] = 0.125f * bfhi(qraw.w);
  }
  __builtin_amdgcn_wave_barrier();
  // phase 1: 8 steps; step jj covers keys 8*jj + ksub
  float l[8];
  int offr[8];
  #pragma unroll
  for (int jj = 0; jj < 8; ++jj) {
    const int offj = off_s[w][8 * jj + ksub];
    offr[jj] = offj;
    uint4 raw = *reinterpret_cast<const uint4*>(k + offj + hbase);
    float pl = qv[0] * bflo(raw.x) + qv[1] * bfhi(raw.x)
             + qv[2] * bflo(raw.y) + qv[3] * bfhi(raw.y)
             + qv[4] * bflo(raw.z) + qv[5] * bfhi(raw.z)
             + qv[6] * bflo(raw.w) + qv[7] * bfhi(raw.w);
    pl += __shfl_xor(pl, 1);
    pl += __shfl_xor(pl, 2);
    pl += __shfl_xor(pl, 4);
    l[jj] = pl;  // logit of key 8*jj+ksub, broadcast within 8-lane group
  }
  // softmax over 64 keys: 8 local + cross-ksub (xor 8,16,32)
  float m = l[0];
  #pragma unroll
  for (int jj = 1; jj < 8; ++jj) m = fmaxf(m, l[jj]);
  m = fmaxf(m, __shfl_xor(m, 8));
  m = fmaxf(m, __shfl_xor(m, 16));
  m = fmaxf(m, __shfl_xor(m, 32));
  float sum = 0.f;
  #pragma unroll
  for (int jj = 0; jj < 8; ++jj) {
    l[jj] = __expf(l[jj] - m);
    sum += l[jj];
  }
  sum += __shfl_xor(sum, 8);
  sum += __shfl_xor(sum, 16);
  sum += __shfl_xor(sum, 32);
  const float rs = 1.0f / sum;
  // phase 2: same pattern on V
  float a[8] = {0.f, 0.f, 0.f, 0.f, 0.f, 0.f, 0.f, 0.f};
  #pragma unroll
  for (int jj = 0; jj < 8; ++jj) {
    uint4 raw = *reinterpret_cast<const uint4*>(v + offr[jj] + hbase);
    const float p = l[jj] * rs;
    a[0] += p * bflo(raw.x); a[1] += p * bfhi(raw.x);
    a[2] += p * bflo(raw.y); a[3] += p * bfhi(raw.y);
    a[4] += p * bflo(raw.z); a[5] += p * bfhi(raw.z);
    a[6] += p * bflo(raw.w); a[7] += p * bfhi(raw.w);
  }
  #pragma unroll
  for (int o = 8; o <= 32; o <<= 1) {
    #pragma unroll
    for (int z = 0; z < 8; ++z) a[z] += __shfl_xor(a[z], o);
  }
  if (ksub == 0) {
    ushort4 o0, o1;
    o0.x = f2bfu(a[0]); o0.y = f2bfu(a[1]); o0.z = f2bfu(a[2]); o0.w = f2bfu(a[3]);
    o1.x = f2bfu(a[4]); o1.y = f2bfu(a[5]); o1.z = f2bfu(a[6]); o1.w = f2bfu(a[7]);
    ushort4* dst = reinterpret_cast<ushort4*>(attn_out + (size_t)t * C_DIM + hbase);
    dst[0] = o0;
    dst[1] = o1;
  }
}

extern "C" void kernel_launch(void* const* d_in, const int* in_sizes, int n_in,
                              void* d_out, int out_size, void* d_ws, size_t ws_size,
                              hipStream_t stream) {
  const float* x   = (const float*)d_in[0];
  const float* Wq  = (const float*)d_in[1];
  const float* bq  = (const float*)d_in[2];
  const float* Wk  = (const float*)d_in[3];
  const float* bk  = (const float*)d_in[4];
  const float* Wv  = (const float*)d_in[5];
  const float* bv  = (const float*)d_in[6];
  const float* Wo  = (const float*)d_in[7];
  const float* bo  = (const float*)d_in[8];
  const float* Wks = (const float*)d_in[9];
  const float* bks = (const float*)d_in[10];
  float* out = (float*)d_out;

  char* ws = (char*)d_ws;
  size_t off = 0;
  float* scores = (float*)(ws + off); off += 8192;
  int*   sorted = (int*)(ws + off);   off += 8192;
  int*   topk   = (int*)(ws + off);   off += (size_t)T_DIM * KSP * 4;
  unsigned short* xb  = (unsigned short*)(ws + off); off += (size_t)T_DIM * C_DIM * 2;
  unsigned short* Wqb = (unsigned short*)(ws + off); off += (size_t)C_DIM * C_DIM * 2;
  unsigned short* Wkb = (unsigned short*)(ws + off); off += (size_t)C_DIM * C_DIM * 2;
  unsigned short* Wvb = (unsigned short*)(ws + off); off += (size_t)C_DIM * C_DIM * 2;
  unsigned short* Wob = (unsigned short*)(ws + off); off += (size_t)C_DIM * C_DIM * 2;
  unsigned short* qb  = (unsigned short*)(ws + off); off += (size_t)T_DIM * C_DIM * 2;
  unsigned short* kb  = (unsigned short*)(ws + off); off += (size_t)T_DIM * C_DIM * 2;
  unsigned short* vb  = (unsigned short*)(ws + off); off += (size_t)T_DIM * C_DIM * 2;
  unsigned short* ab  = xb;  // alias: xb dead after gemm_qkv

  const int n4_total = (T_DIM * C_DIM + 4 * C_DIM * C_DIM) / 4;
  convert_all_kernel<<<n4_total / 256, 256, 0, stream>>>(
      x, Wq, Wk, Wv, Wo, xb, Wqb, Wkb, Wvb, Wob);

  scores_kernel<<<T_DIM / 4, 256, 0, stream>>>(x, Wks, bks, scores);
  rank_sort_kernel<<<T_DIM / 4, 256, 0, stream>>>(scores, sorted);
  select_topk_kernel<<<T_DIM / 4, 256, 0, stream>>>(sorted, topk);

  gemm_qkv_kernel<<<3 * (T_DIM / GBM) * (C_DIM / GBN), 256, 0, stream>>>(
      xb, Wqb, Wkb, Wvb, bq, bk, bv, qb, kb, vb);

  attn_kernel<<<T_DIM * 4, 256, 0, stream>>>(qb, kb, vb, topk, ab);

  gemm_o_f32_kernel<<<(T_DIM / GBM) * (C_DIM / GBN), 256, 0, stream>>>(
      ab, Wob, bo, out);
}

// Round 13
// 167.728 us; speedup vs baseline: 1.4471x; 1.0253x over previous
//
#include <hip/hip_runtime.h>
#include <hip/hip_bf16.h>
#include <cstdint>
#include <cstddef>

#define T_DIM 2048
#define C_DIM 1024
#define NH 16
#define HS 64
#define KSP 64

// 128x64 GEMM tile, BK=128 (barrier halving for short-K shapes),
// unpadded XOR-swizzled LDS, global_load_lds staging
#define GBM 128
#define GBN 64
#define GBK 128

typedef short short8 __attribute__((ext_vector_type(8)));
typedef float f32x4 __attribute__((ext_vector_type(4)));

__device__ __forceinline__ float bfu2f(unsigned short u) {
  unsigned v = ((unsigned)u) << 16;
  return __builtin_bit_cast(float, v);
}
__device__ __forceinline__ unsigned short f2bfu(float f) {
  unsigned u = __builtin_bit_cast(unsigned, f);
  unsigned r = (u + 0x7fffu + ((u >> 16) & 1u)) >> 16;
  return (unsigned short)r;
}
__device__ __forceinline__ float bflo(unsigned u) {
  return __builtin_bit_cast(float, u << 16);
}
__device__ __forceinline__ float bfhi(unsigned u) {
  return __builtin_bit_cast(float, u & 0xffff0000u);
}

#define GLOAD_LDS16(gp, lp)                                                  \
  __builtin_amdgcn_global_load_lds(                                          \
      (const __attribute__((address_space(1))) void*)(gp),                   \
      (__attribute__((address_space(3))) void*)(lp), 16, 0, 0)

// ---- fused: float32->bf16 conversion of x + 4 weights, PLUS key_scores ----
// blocks [0, NCONV): conversion; blocks [NCONV, NCONV+512): scores (wave/row)
#define NCONV ((T_DIM * C_DIM + 4 * C_DIM * C_DIM) / 4 / 256)  // 6144
__global__ __launch_bounds__(256) void convert_scores_kernel(
    const float* __restrict__ x, const float* __restrict__ Wq,
    const float* __restrict__ Wk, const float* __restrict__ Wv,
    const float* __restrict__ Wo, const float* __restrict__ Wks,
    const float* __restrict__ bks,
    unsigned short* __restrict__ xb, unsigned short* __restrict__ Wqb,
    unsigned short* __restrict__ Wkb, unsigned short* __restrict__ Wvb,
    unsigned short* __restrict__ Wob, float* __restrict__ scores) {
  if (blockIdx.x >= NCONV) {
    const int t = (blockIdx.x - NCONV) * 4 + (threadIdx.x >> 6);
    const int lane = threadIdx.x & 63;
    const float* xrow = x + (size_t)t * C_DIM;
    float acc = 0.f;
    #pragma unroll 4
    for (int i = lane; i < C_DIM; i += 64)
      acc += xrow[i] * Wks[i];
    #pragma unroll
    for (int o = 32; o; o >>= 1) acc += __shfl_xor(acc, o);
    if (lane == 0) scores[t] = acc + bks[0];
    return;
  }
  const int i = blockIdx.x * 256 + threadIdx.x;
  const int NX4 = T_DIM * C_DIM / 4;
  const int NW4 = C_DIM * C_DIM / 4;
  const float* src;
  unsigned short* dst;
  int j = i;
  if (j < NX4) { src = x; dst = xb; }
  else {
    j -= NX4;
    int w = j / NW4;
    j -= w * NW4;
    src = (w == 0) ? Wq : (w == 1) ? Wk : (w == 2) ? Wv : Wo;
    dst = (w == 0) ? Wqb : (w == 1) ? Wkb : (w == 2) ? Wvb : Wob;
  }
  float4 f = reinterpret_cast<const float4*>(src)[j];
  ushort4 o;
  o.x = f2bfu(f.x); o.y = f2bfu(f.y); o.z = f2bfu(f.z); o.w = f2bfu(f.w);
  reinterpret_cast<ushort4*>(dst)[j] = o;
}

// ---- rank-by-counting sort: one wave per element, lane-parallel scan ----
__global__ __launch_bounds__(256) void rank_sort_kernel(
    const float* __restrict__ scores, int* __restrict__ sorted_idx) {
  __shared__ float ss[T_DIM];
  const int tid = threadIdx.x;
  for (int j = tid; j < T_DIM; j += 256) ss[j] = scores[j];
  __syncthreads();
  const int w = tid >> 6, lane = tid & 63;
  const int i = blockIdx.x * 4 + w;
  const float si = ss[i];
  int rank = 0;
  #pragma unroll
  for (int step = 0; step < T_DIM / 64; ++step) {
    const int j = step * 64 + lane;
    const float sj = ss[j];
    rank += (int)((sj > si) || (sj == si && j < i));
  }
  #pragma unroll
  for (int o = 32; o; o >>= 1) rank += __shfl_xor(rank, o);
  if (lane == 0) sorted_idx[rank] = i;
}

// ---- per-t top-64 selection: one wave per t, ballot + prefix-popcount ----
__global__ __launch_bounds__(256) void select_topk_kernel(
    const int* __restrict__ sorted_idx, int* __restrict__ topk) {
  __shared__ int ss[T_DIM];
  const int tid = threadIdx.x;
  for (int i = tid; i < T_DIM; i += 256) {
    int s = sorted_idx[i];
    ss[i] = (s < 0) ? 0 : (s > T_DIM - 1 ? T_DIM - 1 : s);
  }
  __syncthreads();
  const int t = blockIdx.x * 4 + (tid >> 6);
  const int lane = tid & 63;
  if (t <= 63) {
    topk[(size_t)t * KSP + lane] = (lane < t) ? lane : t;
  } else {
    const unsigned long long lt_mask = (1ull << lane) - 1ull;
    int count = 0;
    for (int chunk = 0; chunk < T_DIM / 64 && count < KSP; ++chunk) {
      int s = ss[chunk * 64 + lane];
      bool ok = (s <= t);
      unsigned long long m = __ballot(ok);
      int pos = count + __popcll(m & lt_mask);
      if (ok && pos < KSP) topk[(size_t)t * KSP + pos] = s;
      count += __popcll(m);
    }
  }
}

// ---- GEMM body: 128x64 tile, BK=128; global_load_lds + XOR swizzle.
// Row = 256B = 16 chunks of 16B. Logical chunk q of row rho stored at
// physical chunk q^(rho&7) (stays within its 8-chunk half).
// Staging: one GLOAD covers 4 rows (16 lanes each); lane l -> row l>>4,
// physical chunk l&15, global logical chunk (l&15)^(row&7).
// Frag read: lane r reads logical chunk ks*4+quad -> physical ^(r&7):
// 8 distinct chunks over 16 lanes -> 2-way bank alias (free). ----
__device__ __forceinline__ void gemm_body_128x64(
    const unsigned short* __restrict__ A, const unsigned short* __restrict__ W,
    f32x4 acc[4][2], int bm, int bn, int tid) {
  __shared__ unsigned short As[GBM * GBK];  // 32 KB
  __shared__ unsigned short Ws[GBN * GBK];  // 16 KB
  const int w = tid >> 6, lane = tid & 63;
  const int quad = lane >> 4, r = lane & 15;
  const int wm = (w >> 1) * 64, wn = (w & 1) * 32;
  const int sub = lane >> 4;       // 0..3 row within 4-row group
  const int c = lane & 15;         // 0..15 chunk
  const unsigned short* Arow[8];
  const unsigned short* Wrow[4];
  #pragma unroll
  for (int i = 0; i < 8; ++i) {
    const int row = w * 32 + i * 4 + sub;
    Arow[i] = A + (size_t)(bm * GBM + row) * C_DIM + ((c ^ (row & 7)) * 8);
  }
  #pragma unroll
  for (int i = 0; i < 4; ++i) {
    const int row = w * 16 + i * 4 + sub;
    Wrow[i] = W + (size_t)(bn * GBN + row) * C_DIM + ((c ^ (row & 7)) * 8);
  }
  for (int kb = 0; kb < C_DIM; kb += GBK) {
    #pragma unroll
    for (int i = 0; i < 8; ++i)
      GLOAD_LDS16(Arow[i] + kb, &As[(w * 32 + i * 4) * GBK]);
    #pragma unroll
    for (int i = 0; i < 4; ++i)
      GLOAD_LDS16(Wrow[i] + kb, &Ws[(w * 16 + i * 4) * GBK]);
    __syncthreads();
    #pragma unroll
    for (int ks = 0; ks < 4; ++ks) {
      const int pc = ((ks * 4 + quad) ^ (r & 7)) * 8;  // physical col offset
      short8 af[4], bfr[2];
      #pragma unroll
      for (int mi = 0; mi < 4; ++mi)
        af[mi] = *reinterpret_cast<const short8*>(&As[(wm + mi * 16 + r) * GBK + pc]);
      #pragma unroll
      for (int ni = 0; ni < 2; ++ni)
        bfr[ni] = *reinterpret_cast<const short8*>(&Ws[(wn + ni * 16 + r) * GBK + pc]);
      #pragma unroll
      for (int mi = 0; mi < 4; ++mi)
        #pragma unroll
        for (int ni = 0; ni < 2; ++ni)
          acc[mi][ni] = __builtin_amdgcn_mfma_f32_16x16x32_bf16(af[mi], bfr[ni], acc[mi][ni], 0, 0, 0);
    }
    __syncthreads();
  }
}

// ---- fused QKV projection: 3 GEMMs in one launch, bf16 out ----
__global__ __launch_bounds__(256) void gemm_qkv_kernel(
    const unsigned short* __restrict__ A,
    const unsigned short* __restrict__ Wq, const unsigned short* __restrict__ Wk,
    const unsigned short* __restrict__ Wv,
    const float* __restrict__ bq, const float* __restrict__ bk,
    const float* __restrict__ bv,
    unsigned short* __restrict__ qo, unsigned short* __restrict__ ko,
    unsigned short* __restrict__ vo) {
  const int per = (T_DIM / GBM) * (C_DIM / GBN);  // 256
  const int which = blockIdx.x / per;
  const int rem = blockIdx.x % per;
  const int bm = rem / (C_DIM / GBN);
  const int bn = rem % (C_DIM / GBN);
  const unsigned short* W = (which == 0) ? Wq : (which == 1) ? Wk : Wv;
  const float* bias = (which == 0) ? bq : (which == 1) ? bk : bv;
  unsigned short* out = (which == 0) ? qo : (which == 1) ? ko : vo;
  const int tid = threadIdx.x;
  f32x4 acc[4][2] = {};
  gemm_body_128x64(A, W, acc, bm, bn, tid);
  const int w = tid >> 6, lane = tid & 63;
  const int quad = lane >> 4, r = lane & 15;
  const int wm = (w >> 1) * 64, wn = (w & 1) * 32;
  #pragma unroll
  for (int mi = 0; mi < 4; ++mi) {
    #pragma unroll
    for (int ni = 0; ni < 2; ++ni) {
      const int col = bn * GBN + wn + ni * 16 + r;
      const float bf = bias[col];
      #pragma unroll
      for (int i = 0; i < 4; ++i) {
        const int row = bm * GBM + wm + mi * 16 + quad * 4 + i;
        out[(size_t)row * C_DIM + col] = f2bfu(acc[mi][ni][i] + bf);
      }
    }
  }
}

// ---- output projection GEMM, fp32 out ----
__global__ __launch_bounds__(256) void gemm_o_f32_kernel(
    const unsigned short* __restrict__ A, const unsigned short* __restrict__ W,
    const float* __restrict__ bias, float* __restrict__ out) {
  const int tid = threadIdx.x;
  const int bm = blockIdx.x / (C_DIM / GBN);
  const int bn = blockIdx.x % (C_DIM / GBN);
  f32x4 acc[4][2] = {};
  gemm_body_128x64(A, W, acc, bm, bn, tid);
  const int w = tid >> 6, lane = tid & 63;
  const int quad = lane >> 4, r = lane & 15;
  const int wm = (w >> 1) * 64, wn = (w & 1) * 32;
  #pragma unroll
  for (int mi = 0; mi < 4; ++mi) {
    #pragma unroll
    for (int ni = 0; ni < 2; ++ni) {
      const int col = bn * GBN + wn + ni * 16 + r;
      const float bf = bias[col];
      #pragma unroll
      for (int i = 0; i < 4; ++i) {
        const int row = bm * GBM + wm + mi * 16 + quad * 4 + i;
        out[(size_t)row * C_DIM + col] = acc[mi][ni][i] + bf;
      }
    }
  }
}

// ---- sparse attention v7: block per (t, head-group), one wave per head ----
__global__ __launch_bounds__(256) void attn_kernel(
    const unsigned short* __restrict__ q, const unsigned short* __restrict__ k,
    const unsigned short* __restrict__ v, const int* __restrict__ topk,
    unsigned short* __restrict__ attn_out) {
  __shared__ int off_s[4][KSP];
  const int t = blockIdx.x >> 2;
  const int hg = blockIdx.x & 3;
  const int tid = threadIdx.x;
  const int w = tid >> 6, lane = tid & 63;
  const int h = hg * 4 + w;
  const int c8 = lane & 7;
  const int ksub = lane >> 3;
  {
    int s = topk[(size_t)t * KSP + lane];
    s = (s < 0) ? 0 : (s > t ? t : s);
    off_s[w][lane] = s * C_DIM;
  }
  const int hbase = h * HS + 8 * c8;
  float qv[8];
  {
    uint4 qraw = *reinterpret_cast<const uint4*>(q + (size_t)t * C_DIM + hbase);
    qv[0] = 0.125f * bflo(qraw.x); qv[1] = 0.125f * bfhi(qraw.x);
    qv[2] = 0.125f * bflo(qraw.y); qv[3] = 0.125f * bfhi(qraw.y);
    qv[4] = 0.125f * bflo(qraw.z); qv[5] = 0.125f * bfhi(qraw.z);
    qv[6] = 0.125f * bflo(qraw.w); qv[7] = 0.125f * bfhi(qraw.w);
  }
  __builtin_amdgcn_wave_barrier();
  float l[8];
  int offr[8];
  #pragma unroll
  for (int jj = 0; jj < 8; ++jj) {
    const int offj = off_s[w][8 * jj + ksub];
    offr[jj] = offj;
    uint4 raw = *reinterpret_cast<const uint4*>(k + offj + hbase);
    float pl = qv[0] * bflo(raw.x) + qv[1] * bfhi(raw.x)
             + qv[2] * bflo(raw.y) + qv[3] * bfhi(raw.y)
             + qv[4] * bflo(raw.z) + qv[5] * bfhi(raw.z)
             + qv[6] * bflo(raw.w) + qv[7] * bfhi(raw.w);
    pl += __shfl_xor(pl, 1);
    pl += __shfl_xor(pl, 2);
    pl += __shfl_xor(pl, 4);
    l[jj] = pl;
  }
  float m = l[0];
  #pragma unroll
  for (int jj = 1; jj < 8; ++jj) m = fmaxf(m, l[jj]);
  m = fmaxf(m, __shfl_xor(m, 8));
  m = fmaxf(m, __shfl_xor(m, 16));
  m = fmaxf(m, __shfl_xor(m, 32));
  float sum = 0.f;
  #pragma unroll
  for (int jj = 0; jj < 8; ++jj) {
    l[jj] = __expf(l[jj] - m);
    sum += l[jj];
  }
  sum += __shfl_xor(sum, 8);
  sum += __shfl_xor(sum, 16);
  sum += __shfl_xor(sum, 32);
  const float rs = 1.0f / sum;
  float a[8] = {0.f, 0.f, 0.f, 0.f, 0.f, 0.f, 0.f, 0.f};
  #pragma unroll
  for (int jj = 0; jj < 8; ++jj) {
    uint4 raw = *reinterpret_cast<const uint4*>(v + offr[jj] + hbase);
    const float p = l[jj] * rs;
    a[0] += p * bflo(raw.x); a[1] += p * bfhi(raw.x);
    a[2] += p * bflo(raw.y); a[3] += p * bfhi(raw.y);
    a[4] += p * bflo(raw.z); a[5] += p * bfhi(raw.z);
    a[6] += p * bflo(raw.w); a[7] += p * bfhi(raw.w);
  }
  #pragma unroll
  for (int o = 8; o <= 32; o <<= 1) {
    #pragma unroll
    for (int z = 0; z < 8; ++z) a[z] += __shfl_xor(a[z], o);
  }
  if (ksub == 0) {
    ushort4 o0, o1;
    o0.x = f2bfu(a[0]); o0.y = f2bfu(a[1]); o0.z = f2bfu(a[2]); o0.w = f2bfu(a[3]);
    o1.x = f2bfu(a[4]); o1.y = f2bfu(a[5]); o1.z = f2bfu(a[6]); o1.w = f2bfu(a[7]);
    ushort4* dst = reinterpret_cast<ushort4*>(attn_out + (size_t)t * C_DIM + hbase);
    dst[0] = o0;
    dst[1] = o1;
  }
}

extern "C" void kernel_launch(void* const* d_in, const int* in_sizes, int n_in,
                              void* d_out, int out_size, void* d_ws, size_t ws_size,
                              hipStream_t stream) {
  const float* x   = (const float*)d_in[0];
  const float* Wq  = (const float*)d_in[1];
  const float* bq  = (const float*)d_in[2];
  const float* Wk  = (const float*)d_in[3];
  const float* bk  = (const float*)d_in[4];
  const float* Wv  = (const float*)d_in[5];
  const float* bv  = (const float*)d_in[6];
  const float* Wo  = (const float*)d_in[7];
  const float* bo  = (const float*)d_in[8];
  const float* Wks = (const float*)d_in[9];
  const float* bks = (const float*)d_in[10];
  float* out = (float*)d_out;

  char* ws = (char*)d_ws;
  size_t off = 0;
  float* scores = (float*)(ws + off); off += 8192;
  int*   sorted = (int*)(ws + off);   off += 8192;
  int*   topk   = (int*)(ws + off);   off += (size_t)T_DIM * KSP * 4;
  unsigned short* xb  = (unsigned short*)(ws + off); off += (size_t)T_DIM * C_DIM * 2;
  unsigned short* Wqb = (unsigned short*)(ws + off); off += (size_t)C_DIM * C_DIM * 2;
  unsigned short* Wkb = (unsigned short*)(ws + off); off += (size_t)C_DIM * C_DIM * 2;
  unsigned short* Wvb = (unsigned short*)(ws + off); off += (size_t)C_DIM * C_DIM * 2;
  unsigned short* Wob = (unsigned short*)(ws + off); off += (size_t)C_DIM * C_DIM * 2;
  unsigned short* qb  = (unsigned short*)(ws + off); off += (size_t)T_DIM * C_DIM * 2;
  unsigned short* kb  = (unsigned short*)(ws + off); off += (size_t)T_DIM * C_DIM * 2;
  unsigned short* vb  = (unsigned short*)(ws + off); off += (size_t)T_DIM * C_DIM * 2;
  unsigned short* ab  = xb;  // alias: xb dead after gemm_qkv

  // conversion + scores fused: 6144 convert blocks + 512 score blocks
  convert_scores_kernel<<<NCONV + T_DIM / 4, 256, 0, stream>>>(
      x, Wq, Wk, Wv, Wo, Wks, bks, xb, Wqb, Wkb, Wvb, Wob, scores);

  rank_sort_kernel<<<T_DIM / 4, 256, 0, stream>>>(scores, sorted);
  select_topk_kernel<<<T_DIM / 4, 256, 0, stream>>>(sorted, topk);

  gemm_qkv_kernel<<<3 * (T_DIM / GBM) * (C_DIM / GBN), 256, 0, stream>>>(
      xb, Wqb, Wkb, Wvb, bq, bk, bv, qb, kb, vb);

  attn_kernel<<<T_DIM * 4, 256, 0, stream>>>(qb, kb, vb, topk, ab);

  gemm_o_f32_kernel<<<(T_DIM / GBM) * (C_DIM / GBN), 256, 0, stream>>>(
      ab, Wob, bo, out);
}

// Round 14
// 165.456 us; speedup vs baseline: 1.4670x; 1.0137x over previous
//
#include <hip/hip_runtime.h>
#include <hip/hip_bf16.h>
#include <cstdint>
#include <cstddef>

#define T_DIM 2048
#define C_DIM 1024
#define NH 16
#define HS 64
#define KSP 64

// 128x64 GEMM tile, BK=128, unpadded XOR-swizzled LDS, global_load_lds staging
#define GBM 128
#define GBN 64
#define GBK 128

typedef short short8 __attribute__((ext_vector_type(8)));
typedef float f32x4 __attribute__((ext_vector_type(4)));

__device__ __forceinline__ float bfu2f(unsigned short u) {
  unsigned v = ((unsigned)u) << 16;
  return __builtin_bit_cast(float, v);
}
__device__ __forceinline__ unsigned short f2bfu(float f) {
  unsigned u = __builtin_bit_cast(unsigned, f);
  unsigned r = (u + 0x7fffu + ((u >> 16) & 1u)) >> 16;
  return (unsigned short)r;
}
__device__ __forceinline__ float bflo(unsigned u) {
  return __builtin_bit_cast(float, u << 16);
}
__device__ __forceinline__ float bfhi(unsigned u) {
  return __builtin_bit_cast(float, u & 0xffff0000u);
}

#define GLOAD_LDS16(gp, lp)                                                  \
  __builtin_amdgcn_global_load_lds(                                          \
      (const __attribute__((address_space(1))) void*)(gp),                   \
      (__attribute__((address_space(3))) void*)(lp), 16, 0, 0)

// ---- fused: key_scores (blocks [0,512)) + f32->bf16 conversion (rest) ----
#define NSCORE (T_DIM / 4)  // 512
#define NCONV ((T_DIM * C_DIM + 4 * C_DIM * C_DIM) / 4 / 256)  // 6144
__global__ __launch_bounds__(256) void convert_scores_kernel(
    const float* __restrict__ x, const float* __restrict__ Wq,
    const float* __restrict__ Wk, const float* __restrict__ Wv,
    const float* __restrict__ Wo, const float* __restrict__ Wks,
    const float* __restrict__ bks,
    unsigned short* __restrict__ xb, unsigned short* __restrict__ Wqb,
    unsigned short* __restrict__ Wkb, unsigned short* __restrict__ Wvb,
    unsigned short* __restrict__ Wob, float* __restrict__ scores) {
  if (blockIdx.x < NSCORE) {
    const int t = blockIdx.x * 4 + (threadIdx.x >> 6);
    const int lane = threadIdx.x & 63;
    const float* xrow = x + (size_t)t * C_DIM;
    float acc = 0.f;
    #pragma unroll 4
    for (int i = lane; i < C_DIM; i += 64)
      acc += xrow[i] * Wks[i];
    #pragma unroll
    for (int o = 32; o; o >>= 1) acc += __shfl_xor(acc, o);
    if (lane == 0) scores[t] = acc + bks[0];
    return;
  }
  const int i = (blockIdx.x - NSCORE) * 256 + threadIdx.x;
  const int NX4 = T_DIM * C_DIM / 4;
  const int NW4 = C_DIM * C_DIM / 4;
  const float* src;
  unsigned short* dst;
  int j = i;
  if (j < NX4) { src = x; dst = xb; }
  else {
    j -= NX4;
    int w = j / NW4;
    j -= w * NW4;
    src = (w == 0) ? Wq : (w == 1) ? Wk : (w == 2) ? Wv : Wo;
    dst = (w == 0) ? Wqb : (w == 1) ? Wkb : (w == 2) ? Wvb : Wob;
  }
  float4 f = reinterpret_cast<const float4*>(src)[j];
  ushort4 o;
  o.x = f2bfu(f.x); o.y = f2bfu(f.y); o.z = f2bfu(f.z); o.w = f2bfu(f.w);
  reinterpret_cast<ushort4*>(dst)[j] = o;
}

// ---- rank-by-counting sort: one wave per element, lane-parallel scan ----
__global__ __launch_bounds__(256) void rank_sort_kernel(
    const float* __restrict__ scores, int* __restrict__ sorted_idx) {
  __shared__ float ss[T_DIM];
  const int tid = threadIdx.x;
  for (int j = tid; j < T_DIM; j += 256) ss[j] = scores[j];
  __syncthreads();
  const int w = tid >> 6, lane = tid & 63;
  const int i = blockIdx.x * 4 + w;
  const float si = ss[i];
  int rank = 0;
  #pragma unroll
  for (int step = 0; step < T_DIM / 64; ++step) {
    const int j = step * 64 + lane;
    const float sj = ss[j];
    rank += (int)((sj > si) || (sj == si && j < i));
  }
  #pragma unroll
  for (int o = 32; o; o >>= 1) rank += __shfl_xor(rank, o);
  if (lane == 0) sorted_idx[rank] = i;
}

// ---- per-t top-64 selection: one wave per t, ballot + prefix-popcount ----
__global__ __launch_bounds__(256) void select_topk_kernel(
    const int* __restrict__ sorted_idx, int* __restrict__ topk) {
  __shared__ int ss[T_DIM];
  const int tid = threadIdx.x;
  for (int i = tid; i < T_DIM; i += 256) {
    int s = sorted_idx[i];
    ss[i] = (s < 0) ? 0 : (s > T_DIM - 1 ? T_DIM - 1 : s);
  }
  __syncthreads();
  const int t = blockIdx.x * 4 + (tid >> 6);
  const int lane = tid & 63;
  if (t <= 63) {
    topk[(size_t)t * KSP + lane] = (lane < t) ? lane : t;
  } else {
    const unsigned long long lt_mask = (1ull << lane) - 1ull;
    int count = 0;
    for (int chunk = 0; chunk < T_DIM / 64 && count < KSP; ++chunk) {
      int s = ss[chunk * 64 + lane];
      bool ok = (s <= t);
      unsigned long long m = __ballot(ok);
      int pos = count + __popcll(m & lt_mask);
      if (ok && pos < KSP) topk[(size_t)t * KSP + pos] = s;
      count += __popcll(m);
    }
  }
}

// ---- GEMM body: 128x64 tile, BK=128; global_load_lds + XOR swizzle ----
__device__ __forceinline__ void gemm_body_128x64(
    const unsigned short* __restrict__ A, const unsigned short* __restrict__ W,
    f32x4 acc[4][2], int bm, int bn, int tid) {
  __shared__ unsigned short As[GBM * GBK];  // 32 KB
  __shared__ unsigned short Ws[GBN * GBK];  // 16 KB
  const int w = tid >> 6, lane = tid & 63;
  const int quad = lane >> 4, r = lane & 15;
  const int wm = (w >> 1) * 64, wn = (w & 1) * 32;
  const int sub = lane >> 4;       // 0..3 row within 4-row group
  const int c = lane & 15;         // 0..15 chunk
  const unsigned short* Arow[8];
  const unsigned short* Wrow[4];
  #pragma unroll
  for (int i = 0; i < 8; ++i) {
    const int row = w * 32 + i * 4 + sub;
    Arow[i] = A + (size_t)(bm * GBM + row) * C_DIM + ((c ^ (row & 7)) * 8);
  }
  #pragma unroll
  for (int i = 0; i < 4; ++i) {
    const int row = w * 16 + i * 4 + sub;
    Wrow[i] = W + (size_t)(bn * GBN + row) * C_DIM + ((c ^ (row & 7)) * 8);
  }
  for (int kb = 0; kb < C_DIM; kb += GBK) {
    #pragma unroll
    for (int i = 0; i < 8; ++i)
      GLOAD_LDS16(Arow[i] + kb, &As[(w * 32 + i * 4) * GBK]);
    #pragma unroll
    for (int i = 0; i < 4; ++i)
      GLOAD_LDS16(Wrow[i] + kb, &Ws[(w * 16 + i * 4) * GBK]);
    __syncthreads();
    #pragma unroll
    for (int ks = 0; ks < 4; ++ks) {
      const int pc = ((ks * 4 + quad) ^ (r & 7)) * 8;
      short8 af[4], bfr[2];
      #pragma unroll
      for (int mi = 0; mi < 4; ++mi)
        af[mi] = *reinterpret_cast<const short8*>(&As[(wm + mi * 16 + r) * GBK + pc]);
      #pragma unroll
      for (int ni = 0; ni < 2; ++ni)
        bfr[ni] = *reinterpret_cast<const short8*>(&Ws[(wn + ni * 16 + r) * GBK + pc]);
      #pragma unroll
      for (int mi = 0; mi < 4; ++mi)
        #pragma unroll
        for (int ni = 0; ni < 2; ++ni)
          acc[mi][ni] = __builtin_amdgcn_mfma_f32_16x16x32_bf16(af[mi], bfr[ni], acc[mi][ni], 0, 0, 0);
    }
    __syncthreads();
  }
}

// ---- fused QKV projection: 3 GEMMs in one launch, bf16 out ----
__global__ __launch_bounds__(256) void gemm_qkv_kernel(
    const unsigned short* __restrict__ A,
    const unsigned short* __restrict__ Wq, const unsigned short* __restrict__ Wk,
    const unsigned short* __restrict__ Wv,
    const float* __restrict__ bq, const float* __restrict__ bk,
    const float* __restrict__ bv,
    unsigned short* __restrict__ qo, unsigned short* __restrict__ ko,
    unsigned short* __restrict__ vo) {
  const int per = (T_DIM / GBM) * (C_DIM / GBN);  // 256
  const int which = blockIdx.x / per;
  const int rem = blockIdx.x % per;
  const int bm = rem / (C_DIM / GBN);
  const int bn = rem % (C_DIM / GBN);
  const unsigned short* W = (which == 0) ? Wq : (which == 1) ? Wk : Wv;
  const float* bias = (which == 0) ? bq : (which == 1) ? bk : bv;
  unsigned short* out = (which == 0) ? qo : (which == 1) ? ko : vo;
  const int tid = threadIdx.x;
  f32x4 acc[4][2] = {};
  gemm_body_128x64(A, W, acc, bm, bn, tid);
  const int w = tid >> 6, lane = tid & 63;
  const int quad = lane >> 4, r = lane & 15;
  const int wm = (w >> 1) * 64, wn = (w & 1) * 32;
  #pragma unroll
  for (int mi = 0; mi < 4; ++mi) {
    #pragma unroll
    for (int ni = 0; ni < 2; ++ni) {
      const int col = bn * GBN + wn + ni * 16 + r;
      const float bf = bias[col];
      #pragma unroll
      for (int i = 0; i < 4; ++i) {
        const int row = bm * GBM + wm + mi * 16 + quad * 4 + i;
        out[(size_t)row * C_DIM + col] = f2bfu(acc[mi][ni][i] + bf);
      }
    }
  }
}

// ---- output projection GEMM, fp32 out ----
__global__ __launch_bounds__(256) void gemm_o_f32_kernel(
    const unsigned short* __restrict__ A, const unsigned short* __restrict__ W,
    const float* __restrict__ bias, float* __restrict__ out) {
  const int tid = threadIdx.x;
  const int bm = blockIdx.x / (C_DIM / GBN);
  const int bn = blockIdx.x % (C_DIM / GBN);
  f32x4 acc[4][2] = {};
  gemm_body_128x64(A, W, acc, bm, bn, tid);
  const int w = tid >> 6, lane = tid & 63;
  const int quad = lane >> 4, r = lane & 15;
  const int wm = (w >> 1) * 64, wn = (w & 1) * 32;
  #pragma unroll
  for (int mi = 0; mi < 4; ++mi) {
    #pragma unroll
    for (int ni = 0; ni < 2; ++ni) {
      const int col = bn * GBN + wn + ni * 16 + r;
      const float bf = bias[col];
      #pragma unroll
      for (int i = 0; i < 4; ++i) {
        const int row = bm * GBM + wm + mi * 16 + quad * 4 + i;
        out[(size_t)row * C_DIM + col] = acc[mi][ni][i] + bf;
      }
    }
  }
}

// ---- sparse attention v8: block per (t, head-group), one wave per head.
// Lane = (ksub=lane>>3, c8=lane&7). ALL 16 gathers (8 K + 8 V) issue
// up-front; phase 1 / softmax / phase 2 are then pure VALU on registers. ----
__global__ __launch_bounds__(256) void attn_kernel(
    const unsigned short* __restrict__ q, const unsigned short* __restrict__ k,
    const unsigned short* __restrict__ v, const int* __restrict__ topk,
    unsigned short* __restrict__ attn_out) {
  __shared__ int off_s[4][KSP];
  const int t = blockIdx.x >> 2;
  const int hg = blockIdx.x & 3;
  const int tid = threadIdx.x;
  const int w = tid >> 6, lane = tid & 63;
  const int h = hg * 4 + w;
  const int c8 = lane & 7;
  const int ksub = lane >> 3;
  {
    int s = topk[(size_t)t * KSP + lane];
    s = (s < 0) ? 0 : (s > t ? t : s);
    off_s[w][lane] = s * C_DIM;
  }
  const int hbase = h * HS + 8 * c8;
  float qv[8];
  {
    uint4 qraw = *reinterpret_cast<const uint4*>(q + (size_t)t * C_DIM + hbase);
    qv[0] = 0.125f * bflo(qraw.x); qv[1] = 0.125f * bfhi(qraw.x);
    qv[2] = 0.125f * bflo(qraw.y); qv[3] = 0.125f * bfhi(qraw.y);
    qv[4] = 0.125f * bflo(qraw.z); qv[5] = 0.125f * bfhi(qraw.z);
    qv[6] = 0.125f * bflo(qraw.w); qv[7] = 0.125f * bfhi(qraw.w);
  }
  __builtin_amdgcn_wave_barrier();
  // issue ALL gathers up-front: 8 K + 8 V b128 loads in flight
  int offr[8];
  #pragma unroll
  for (int jj = 0; jj < 8; ++jj) offr[jj] = off_s[w][8 * jj + ksub];
  uint4 kraw[8], vraw[8];
  #pragma unroll
  for (int jj = 0; jj < 8; ++jj)
    kraw[jj] = *reinterpret_cast<const uint4*>(k + offr[jj] + hbase);
  #pragma unroll
  for (int jj = 0; jj < 8; ++jj)
    vraw[jj] = *reinterpret_cast<const uint4*>(v + offr[jj] + hbase);
  // phase 1: logits (pure VALU + shuffles)
  float l[8];
  #pragma unroll
  for (int jj = 0; jj < 8; ++jj) {
    const uint4 raw = kraw[jj];
    float pl = qv[0] * bflo(raw.x) + qv[1] * bfhi(raw.x)
             + qv[2] * bflo(raw.y) + qv[3] * bfhi(raw.y)
             + qv[4] * bflo(raw.z) + qv[5] * bfhi(raw.z)
             + qv[6] * bflo(raw.w) + qv[7] * bfhi(raw.w);
    pl += __shfl_xor(pl, 1);
    pl += __shfl_xor(pl, 2);
    pl += __shfl_xor(pl, 4);
    l[jj] = pl;
  }
  // softmax over 64 keys
  float m = l[0];
  #pragma unroll
  for (int jj = 1; jj < 8; ++jj) m = fmaxf(m, l[jj]);
  m = fmaxf(m, __shfl_xor(m, 8));
  m = fmaxf(m, __shfl_xor(m, 16));
  m = fmaxf(m, __shfl_xor(m, 32));
  float sum = 0.f;
  #pragma unroll
  for (int jj = 0; jj < 8; ++jj) {
    l[jj] = __expf(l[jj] - m);
    sum += l[jj];
  }
  sum += __shfl_xor(sum, 8);
  sum += __shfl_xor(sum, 16);
  sum += __shfl_xor(sum, 32);
  const float rs = 1.0f / sum;
  // phase 2: weighted V sum (pure VALU, data already in registers)
  float a[8] = {0.f, 0.f, 0.f, 0.f, 0.f, 0.f, 0.f, 0.f};
  #pragma unroll
  for (int jj = 0; jj < 8; ++jj) {
    const uint4 raw = vraw[jj];
    const float p = l[jj] * rs;
    a[0] += p * bflo(raw.x); a[1] += p * bfhi(raw.x);
    a[2] += p * bflo(raw.y); a[3] += p * bfhi(raw.y);
    a[4] += p * bflo(raw.z); a[5] += p * bfhi(raw.z);
    a[6] += p * bflo(raw.w); a[7] += p * bfhi(raw.w);
  }
  #pragma unroll
  for (int o = 8; o <= 32; o <<= 1) {
    #pragma unroll
    for (int z = 0; z < 8; ++z) a[z] += __shfl_xor(a[z], o);
  }
  if (ksub == 0) {
    ushort4 o0, o1;
    o0.x = f2bfu(a[0]); o0.y = f2bfu(a[1]); o0.z = f2bfu(a[2]); o0.w = f2bfu(a[3]);
    o1.x = f2bfu(a[4]); o1.y = f2bfu(a[5]); o1.z = f2bfu(a[6]); o1.w = f2bfu(a[7]);
    ushort4* dst = reinterpret_cast<ushort4*>(attn_out + (size_t)t * C_DIM + hbase);
    dst[0] = o0;
    dst[1] = o1;
  }
}

extern "C" void kernel_launch(void* const* d_in, const int* in_sizes, int n_in,
                              void* d_out, int out_size, void* d_ws, size_t ws_size,
                              hipStream_t stream) {
  const float* x   = (const float*)d_in[0];
  const float* Wq  = (const float*)d_in[1];
  const float* bq  = (const float*)d_in[2];
  const float* Wk  = (const float*)d_in[3];
  const float* bk  = (const float*)d_in[4];
  const float* Wv  = (const float*)d_in[5];
  const float* bv  = (const float*)d_in[6];
  const float* Wo  = (const float*)d_in[7];
  const float* bo  = (const float*)d_in[8];
  const float* Wks = (const float*)d_in[9];
  const float* bks = (const float*)d_in[10];
  float* out = (float*)d_out;

  char* ws = (char*)d_ws;
  size_t off = 0;
  float* scores = (float*)(ws + off); off += 8192;
  int*   sorted = (int*)(ws + off);   off += 8192;
  int*   topk   = (int*)(ws + off);   off += (size_t)T_DIM * KSP * 4;
  unsigned short* xb  = (unsigned short*)(ws + off); off += (size_t)T_DIM * C_DIM * 2;
  unsigned short* Wqb = (unsigned short*)(ws + off); off += (size_t)C_DIM * C_DIM * 2;
  unsigned short* Wkb = (unsigned short*)(ws + off); off += (size_t)C_DIM * C_DIM * 2;
  unsigned short* Wvb = (unsigned short*)(ws + off); off += (size_t)C_DIM * C_DIM * 2;
  unsigned short* Wob = (unsigned short*)(ws + off); off += (size_t)C_DIM * C_DIM * 2;
  unsigned short* qb  = (unsigned short*)(ws + off); off += (size_t)T_DIM * C_DIM * 2;
  unsigned short* kb  = (unsigned short*)(ws + off); off += (size_t)T_DIM * C_DIM * 2;
  unsigned short* vb  = (unsigned short*)(ws + off); off += (size_t)T_DIM * C_DIM * 2;
  unsigned short* ab  = xb;  // alias: xb dead after gemm_qkv

  convert_scores_kernel<<<NSCORE + NCONV, 256, 0, stream>>>(
      x, Wq, Wk, Wv, Wo, Wks, bks, xb, Wqb, Wkb, Wvb, Wob, scores);

  rank_sort_kernel<<<T_DIM / 4, 256, 0, stream>>>(scores, sorted);
  select_topk_kernel<<<T_DIM / 4, 256, 0, stream>>>(sorted, topk);

  gemm_qkv_kernel<<<3 * (T_DIM / GBM) * (C_DIM / GBN), 256, 0, stream>>>(
      xb, Wqb, Wkb, Wvb, bq, bk, bv, qb, kb, vb);

  attn_kernel<<<T_DIM * 4, 256, 0, stream>>>(qb, kb, vb, topk, ab);

  gemm_o_f32_kernel<<<(T_DIM / GBM) * (C_DIM / GBN), 256, 0, stream>>>(
      ab, Wob, bo, out);
}

// Round 15
// 155.635 us; speedup vs baseline: 1.5595x; 1.0631x over previous
//
#include <hip/hip_runtime.h>
#include <hip/hip_bf16.h>
#include <cstdint>
#include <cstddef>

#define T_DIM 2048
#define C_DIM 1024
#define NH 16
#define HS 64
#define KSP 64

// QKV GEMM: 128x64 tile, BK=128, XOR-swizzled LDS, global_load_lds staging
#define GBM 128
#define GBN 64
#define GBK 128
// o-proj GEMM: 64x64 tile (512 blocks = 2/CU; fixes 1-block/CU stall exposure)
#define OBM 64
#define OBN 64

typedef short short8 __attribute__((ext_vector_type(8)));
typedef float f32x4 __attribute__((ext_vector_type(4)));
typedef _Float16 half2_t __attribute__((ext_vector_type(2)));

__device__ __forceinline__ float bfu2f(unsigned short u) {
  unsigned v = ((unsigned)u) << 16;
  return __builtin_bit_cast(float, v);
}
__device__ __forceinline__ unsigned short f2bfu(float f) {
  unsigned u = __builtin_bit_cast(unsigned, f);
  unsigned r = (u + 0x7fffu + ((u >> 16) & 1u)) >> 16;
  return (unsigned short)r;
}
__device__ __forceinline__ unsigned short f2h(float f) {
  _Float16 h = (_Float16)f;
  return __builtin_bit_cast(unsigned short, h);
}
__device__ __forceinline__ float bflo(unsigned u) {
  return __builtin_bit_cast(float, u << 16);
}
__device__ __forceinline__ float bfhi(unsigned u) {
  return __builtin_bit_cast(float, u & 0xffff0000u);
}

// dot of two f16 pairs accumulating fp32
__device__ __forceinline__ float dot2h(unsigned kbits, unsigned qbits, float acc) {
#if __has_builtin(__builtin_amdgcn_fdot2)
  return __builtin_amdgcn_fdot2(__builtin_bit_cast(half2_t, kbits),
                                __builtin_bit_cast(half2_t, qbits), acc, false);
#else
  half2_t kk = __builtin_bit_cast(half2_t, kbits);
  half2_t qq = __builtin_bit_cast(half2_t, qbits);
  return acc + (float)kk.x * (float)qq.x + (float)kk.y * (float)qq.y;
#endif
}

#define GLOAD_LDS16(gp, lp)                                                  \
  __builtin_amdgcn_global_load_lds(                                          \
      (const __attribute__((address_space(1))) void*)(gp),                   \
      (__attribute__((address_space(3))) void*)(lp), 16, 0, 0)

// ---- fused: key_scores (blocks [0,512)) + f32->bf16 conversion (rest) ----
#define NSCORE (T_DIM / 4)  // 512
#define NCONV ((T_DIM * C_DIM + 4 * C_DIM * C_DIM) / 4 / 256)  // 6144
__global__ __launch_bounds__(256) void convert_scores_kernel(
    const float* __restrict__ x, const float* __restrict__ Wq,
    const float* __restrict__ Wk, const float* __restrict__ Wv,
    const float* __restrict__ Wo, const float* __restrict__ Wks,
    const float* __restrict__ bks,
    unsigned short* __restrict__ xb, unsigned short* __restrict__ Wqb,
    unsigned short* __restrict__ Wkb, unsigned short* __restrict__ Wvb,
    unsigned short* __restrict__ Wob, float* __restrict__ scores) {
  if (blockIdx.x < NSCORE) {
    const int t = blockIdx.x * 4 + (threadIdx.x >> 6);
    const int lane = threadIdx.x & 63;
    const float* xrow = x + (size_t)t * C_DIM;
    float acc = 0.f;
    #pragma unroll 4
    for (int i = lane; i < C_DIM; i += 64)
      acc += xrow[i] * Wks[i];
    #pragma unroll
    for (int o = 32; o; o >>= 1) acc += __shfl_xor(acc, o);
    if (lane == 0) scores[t] = acc + bks[0];
    return;
  }
  const int i = (blockIdx.x - NSCORE) * 256 + threadIdx.x;
  const int NX4 = T_DIM * C_DIM / 4;
  const int NW4 = C_DIM * C_DIM / 4;
  const float* src;
  unsigned short* dst;
  int j = i;
  if (j < NX4) { src = x; dst = xb; }
  else {
    j -= NX4;
    int w = j / NW4;
    j -= w * NW4;
    src = (w == 0) ? Wq : (w == 1) ? Wk : (w == 2) ? Wv : Wo;
    dst = (w == 0) ? Wqb : (w == 1) ? Wkb : (w == 2) ? Wvb : Wob;
  }
  float4 f = reinterpret_cast<const float4*>(src)[j];
  ushort4 o;
  o.x = f2bfu(f.x); o.y = f2bfu(f.y); o.z = f2bfu(f.z); o.w = f2bfu(f.w);
  reinterpret_cast<ushort4*>(dst)[j] = o;
}

// ---- rank-by-counting sort: one wave per element, lane-parallel scan ----
__global__ __launch_bounds__(256) void rank_sort_kernel(
    const float* __restrict__ scores, int* __restrict__ sorted_idx) {
  __shared__ float ss[T_DIM];
  const int tid = threadIdx.x;
  for (int j = tid; j < T_DIM; j += 256) ss[j] = scores[j];
  __syncthreads();
  const int w = tid >> 6, lane = tid & 63;
  const int i = blockIdx.x * 4 + w;
  const float si = ss[i];
  int rank = 0;
  #pragma unroll
  for (int step = 0; step < T_DIM / 64; ++step) {
    const int j = step * 64 + lane;
    const float sj = ss[j];
    rank += (int)((sj > si) || (sj == si && j < i));
  }
  #pragma unroll
  for (int o = 32; o; o >>= 1) rank += __shfl_xor(rank, o);
  if (lane == 0) sorted_idx[rank] = i;
}

// ---- per-t top-64 selection: one wave per t, ballot + prefix-popcount ----
__global__ __launch_bounds__(256) void select_topk_kernel(
    const int* __restrict__ sorted_idx, int* __restrict__ topk) {
  __shared__ int ss[T_DIM];
  const int tid = threadIdx.x;
  for (int i = tid; i < T_DIM; i += 256) {
    int s = sorted_idx[i];
    ss[i] = (s < 0) ? 0 : (s > T_DIM - 1 ? T_DIM - 1 : s);
  }
  __syncthreads();
  const int t = blockIdx.x * 4 + (tid >> 6);
  const int lane = tid & 63;
  if (t <= 63) {
    topk[(size_t)t * KSP + lane] = (lane < t) ? lane : t;
  } else {
    const unsigned long long lt_mask = (1ull << lane) - 1ull;
    int count = 0;
    for (int chunk = 0; chunk < T_DIM / 64 && count < KSP; ++chunk) {
      int s = ss[chunk * 64 + lane];
      bool ok = (s <= t);
      unsigned long long m = __ballot(ok);
      int pos = count + __popcll(m & lt_mask);
      if (ok && pos < KSP) topk[(size_t)t * KSP + pos] = s;
      count += __popcll(m);
    }
  }
}

// ---- GEMM body: 128x64 tile, BK=128; global_load_lds + XOR swizzle ----
__device__ __forceinline__ void gemm_body_128x64(
    const unsigned short* __restrict__ A, const unsigned short* __restrict__ W,
    f32x4 acc[4][2], int bm, int bn, int tid) {
  __shared__ unsigned short As[GBM * GBK];  // 32 KB
  __shared__ unsigned short Ws[GBN * GBK];  // 16 KB
  const int w = tid >> 6, lane = tid & 63;
  const int quad = lane >> 4, r = lane & 15;
  const int wm = (w >> 1) * 64, wn = (w & 1) * 32;
  const int sub = lane >> 4;
  const int c = lane & 15;
  const unsigned short* Arow[8];
  const unsigned short* Wrow[4];
  #pragma unroll
  for (int i = 0; i < 8; ++i) {
    const int row = w * 32 + i * 4 + sub;
    Arow[i] = A + (size_t)(bm * GBM + row) * C_DIM + ((c ^ (row & 7)) * 8);
  }
  #pragma unroll
  for (int i = 0; i < 4; ++i) {
    const int row = w * 16 + i * 4 + sub;
    Wrow[i] = W + (size_t)(bn * GBN + row) * C_DIM + ((c ^ (row & 7)) * 8);
  }
  for (int kb = 0; kb < C_DIM; kb += GBK) {
    #pragma unroll
    for (int i = 0; i < 8; ++i)
      GLOAD_LDS16(Arow[i] + kb, &As[(w * 32 + i * 4) * GBK]);
    #pragma unroll
    for (int i = 0; i < 4; ++i)
      GLOAD_LDS16(Wrow[i] + kb, &Ws[(w * 16 + i * 4) * GBK]);
    __syncthreads();
    #pragma unroll
    for (int ks = 0; ks < 4; ++ks) {
      const int pc = ((ks * 4 + quad) ^ (r & 7)) * 8;
      short8 af[4], bfr[2];
      #pragma unroll
      for (int mi = 0; mi < 4; ++mi)
        af[mi] = *reinterpret_cast<const short8*>(&As[(wm + mi * 16 + r) * GBK + pc]);
      #pragma unroll
      for (int ni = 0; ni < 2; ++ni)
        bfr[ni] = *reinterpret_cast<const short8*>(&Ws[(wn + ni * 16 + r) * GBK + pc]);
      #pragma unroll
      for (int mi = 0; mi < 4; ++mi)
        #pragma unroll
        for (int ni = 0; ni < 2; ++ni)
          acc[mi][ni] = __builtin_amdgcn_mfma_f32_16x16x32_bf16(af[mi], bfr[ni], acc[mi][ni], 0, 0, 0);
    }
    __syncthreads();
  }
}

// ---- fused QKV projection: q,k -> f16; v -> bf16 ----
__global__ __launch_bounds__(256) void gemm_qkv_kernel(
    const unsigned short* __restrict__ A,
    const unsigned short* __restrict__ Wq, const unsigned short* __restrict__ Wk,
    const unsigned short* __restrict__ Wv,
    const float* __restrict__ bq, const float* __restrict__ bk,
    const float* __restrict__ bv,
    unsigned short* __restrict__ qo, unsigned short* __restrict__ ko,
    unsigned short* __restrict__ vo) {
  const int per = (T_DIM / GBM) * (C_DIM / GBN);  // 256
  const int which = blockIdx.x / per;
  const int rem = blockIdx.x % per;
  const int bm = rem / (C_DIM / GBN);
  const int bn = rem % (C_DIM / GBN);
  const unsigned short* W = (which == 0) ? Wq : (which == 1) ? Wk : Wv;
  const float* bias = (which == 0) ? bq : (which == 1) ? bk : bv;
  unsigned short* out = (which == 0) ? qo : (which == 1) ? ko : vo;
  const int tid = threadIdx.x;
  f32x4 acc[4][2] = {};
  gemm_body_128x64(A, W, acc, bm, bn, tid);
  const int w = tid >> 6, lane = tid & 63;
  const int quad = lane >> 4, r = lane & 15;
  const int wm = (w >> 1) * 64, wn = (w & 1) * 32;
  #pragma unroll
  for (int mi = 0; mi < 4; ++mi) {
    #pragma unroll
    for (int ni = 0; ni < 2; ++ni) {
      const int col = bn * GBN + wn + ni * 16 + r;
      const float bf = bias[col];
      #pragma unroll
      for (int i = 0; i < 4; ++i) {
        const int row = bm * GBM + wm + mi * 16 + quad * 4 + i;
        const float val = acc[mi][ni][i] + bf;
        out[(size_t)row * C_DIM + col] = (which == 2) ? f2bfu(val) : f2h(val);
      }
    }
  }
}

// ---- o-proj GEMM body: 64x64 tile, BK=128 (2 blocks/CU occupancy) ----
__device__ __forceinline__ void gemm_body_64x64(
    const unsigned short* __restrict__ A, const unsigned short* __restrict__ W,
    f32x4 acc[2][2], int bm, int bn, int tid) {
  __shared__ unsigned short As[OBM * GBK];  // 16 KB
  __shared__ unsigned short Ws[OBN * GBK];  // 16 KB
  const int w = tid >> 6, lane = tid & 63;
  const int quad = lane >> 4, r = lane & 15;
  const int wm = (w >> 1) * 32, wn = (w & 1) * 32;
  const int sub = lane >> 4;
  const int c = lane & 15;
  const unsigned short* Arow[4];
  const unsigned short* Wrow[4];
  #pragma unroll
  for (int i = 0; i < 4; ++i) {
    const int row = w * 16 + i * 4 + sub;
    Arow[i] = A + (size_t)(bm * OBM + row) * C_DIM + ((c ^ (row & 7)) * 8);
    Wrow[i] = W + (size_t)(bn * OBN + row) * C_DIM + ((c ^ (row & 7)) * 8);
  }
  for (int kb = 0; kb < C_DIM; kb += GBK) {
    #pragma unroll
    for (int i = 0; i < 4; ++i)
      GLOAD_LDS16(Arow[i] + kb, &As[(w * 16 + i * 4) * GBK]);
    #pragma unroll
    for (int i = 0; i < 4; ++i)
      GLOAD_LDS16(Wrow[i] + kb, &Ws[(w * 16 + i * 4) * GBK]);
    __syncthreads();
    #pragma unroll
    for (int ks = 0; ks < 4; ++ks) {
      const int pc = ((ks * 4 + quad) ^ (r & 7)) * 8;
      short8 af[2], bfr[2];
      #pragma unroll
      for (int mi = 0; mi < 2; ++mi)
        af[mi] = *reinterpret_cast<const short8*>(&As[(wm + mi * 16 + r) * GBK + pc]);
      #pragma unroll
      for (int ni = 0; ni < 2; ++ni)
        bfr[ni] = *reinterpret_cast<const short8*>(&Ws[(wn + ni * 16 + r) * GBK + pc]);
      #pragma unroll
      for (int mi = 0; mi < 2; ++mi)
        #pragma unroll
        for (int ni = 0; ni < 2; ++ni)
          acc[mi][ni] = __builtin_amdgcn_mfma_f32_16x16x32_bf16(af[mi], bfr[ni], acc[mi][ni], 0, 0, 0);
    }
    __syncthreads();
  }
}

// ---- output projection GEMM, fp32 out, 64x64 tile ----
__global__ __launch_bounds__(256) void gemm_o_f32_kernel(
    const unsigned short* __restrict__ A, const unsigned short* __restrict__ W,
    const float* __restrict__ bias, float* __restrict__ out) {
  const int tid = threadIdx.x;
  const int bm = blockIdx.x / (C_DIM / OBN);
  const int bn = blockIdx.x % (C_DIM / OBN);
  f32x4 acc[2][2] = {};
  gemm_body_64x64(A, W, acc, bm, bn, tid);
  const int w = tid >> 6, lane = tid & 63;
  const int quad = lane >> 4, r = lane & 15;
  const int wm = (w >> 1) * 32, wn = (w & 1) * 32;
  #pragma unroll
  for (int mi = 0; mi < 2; ++mi) {
    #pragma unroll
    for (int ni = 0; ni < 2; ++ni) {
      const int col = bn * OBN + wn + ni * 16 + r;
      const float bf = bias[col];
      #pragma unroll
      for (int i = 0; i < 4; ++i) {
        const int row = bm * OBM + wm + mi * 16 + quad * 4 + i;
        out[(size_t)row * C_DIM + col] = acc[mi][ni][i] + bf;
      }
    }
  }
}

// ---- sparse attention v9: Q,K f16 (fdot2 path), V bf16.
// Lane = (ksub=lane>>3, c8=lane&7); all 16 gathers issued up-front. ----
__global__ __launch_bounds__(256) void attn_kernel(
    const unsigned short* __restrict__ q, const unsigned short* __restrict__ k,
    const unsigned short* __restrict__ v, const int* __restrict__ topk,
    unsigned short* __restrict__ attn_out) {
  __shared__ int off_s[4][KSP];
  const int t = blockIdx.x >> 2;
  const int hg = blockIdx.x & 3;
  const int tid = threadIdx.x;
  const int w = tid >> 6, lane = tid & 63;
  const int h = hg * 4 + w;
  const int c8 = lane & 7;
  const int ksub = lane >> 3;
  {
    int s = topk[(size_t)t * KSP + lane];
    s = (s < 0) ? 0 : (s > t ? t : s);
    off_s[w][lane] = s * C_DIM;
  }
  const int hbase = h * HS + 8 * c8;
  uint4 qraw = *reinterpret_cast<const uint4*>(q + (size_t)t * C_DIM + hbase);
  __builtin_amdgcn_wave_barrier();
  int offr[8];
  #pragma unroll
  for (int jj = 0; jj < 8; ++jj) offr[jj] = off_s[w][8 * jj + ksub];
  uint4 kraw[8], vraw[8];
  #pragma unroll
  for (int jj = 0; jj < 8; ++jj)
    kraw[jj] = *reinterpret_cast<const uint4*>(k + offr[jj] + hbase);
  #pragma unroll
  for (int jj = 0; jj < 8; ++jj)
    vraw[jj] = *reinterpret_cast<const uint4*>(v + offr[jj] + hbase);
  // phase 1: logits via f16 dot2 (4 per key), scale applied post-dot (exact)
  float l[8];
  #pragma unroll
  for (int jj = 0; jj < 8; ++jj) {
    const uint4 raw = kraw[jj];
    float pl = dot2h(raw.x, qraw.x, 0.f);
    pl = dot2h(raw.y, qraw.y, pl);
    pl = dot2h(raw.z, qraw.z, pl);
    pl = dot2h(raw.w, qraw.w, pl);
    pl *= 0.125f;
    pl += __shfl_xor(pl, 1);
    pl += __shfl_xor(pl, 2);
    pl += __shfl_xor(pl, 4);
    l[jj] = pl;
  }
  // softmax over 64 keys
  float m = l[0];
  #pragma unroll
  for (int jj = 1; jj < 8; ++jj) m = fmaxf(m, l[jj]);
  m = fmaxf(m, __shfl_xor(m, 8));
  m = fmaxf(m, __shfl_xor(m, 16));
  m = fmaxf(m, __shfl_xor(m, 32));
  float sum = 0.f;
  #pragma unroll
  for (int jj = 0; jj < 8; ++jj) {
    l[jj] = __expf(l[jj] - m);
    sum += l[jj];
  }
  sum += __shfl_xor(sum, 8);
  sum += __shfl_xor(sum, 16);
  sum += __shfl_xor(sum, 32);
  const float rs = 1.0f / sum;
  // phase 2: weighted V (bf16) sum
  float a[8] = {0.f, 0.f, 0.f, 0.f, 0.f, 0.f, 0.f, 0.f};
  #pragma unroll
  for (int jj = 0; jj < 8; ++jj) {
    const uint4 raw = vraw[jj];
    const float p = l[jj] * rs;
    a[0] += p * bflo(raw.x); a[1] += p * bfhi(raw.x);
    a[2] += p * bflo(raw.y); a[3] += p * bfhi(raw.y);
    a[4] += p * bflo(raw.z); a[5] += p * bfhi(raw.z);
    a[6] += p * bflo(raw.w); a[7] += p * bfhi(raw.w);
  }
  #pragma unroll
  for (int o = 8; o <= 32; o <<= 1) {
    #pragma unroll
    for (int z = 0; z < 8; ++z) a[z] += __shfl_xor(a[z], o);
  }
  if (ksub == 0) {
    ushort4 o0, o1;
    o0.x = f2bfu(a[0]); o0.y = f2bfu(a[1]); o0.z = f2bfu(a[2]); o0.w = f2bfu(a[3]);
    o1.x = f2bfu(a[4]); o1.y = f2bfu(a[5]); o1.z = f2bfu(a[6]); o1.w = f2bfu(a[7]);
    ushort4* dst = reinterpret_cast<ushort4*>(attn_out + (size_t)t * C_DIM + hbase);
    dst[0] = o0;
    dst[1] = o1;
  }
}

extern "C" void kernel_launch(void* const* d_in, const int* in_sizes, int n_in,
                              void* d_out, int out_size, void* d_ws, size_t ws_size,
                              hipStream_t stream) {
  const float* x   = (const float*)d_in[0];
  const float* Wq  = (const float*)d_in[1];
  const float* bq  = (const float*)d_in[2];
  const float* Wk  = (const float*)d_in[3];
  const float* bk  = (const float*)d_in[4];
  const float* Wv  = (const float*)d_in[5];
  const float* bv  = (const float*)d_in[6];
  const float* Wo  = (const float*)d_in[7];
  const float* bo  = (const float*)d_in[8];
  const float* Wks = (const float*)d_in[9];
  const float* bks = (const float*)d_in[10];
  float* out = (float*)d_out;

  char* ws = (char*)d_ws;
  size_t off = 0;
  float* scores = (float*)(ws + off); off += 8192;
  int*   sorted = (int*)(ws + off);   off += 8192;
  int*   topk   = (int*)(ws + off);   off += (size_t)T_DIM * KSP * 4;
  unsigned short* xb  = (unsigned short*)(ws + off); off += (size_t)T_DIM * C_DIM * 2;
  unsigned short* Wqb = (unsigned short*)(ws + off); off += (size_t)C_DIM * C_DIM * 2;
  unsigned short* Wkb = (unsigned short*)(ws + off); off += (size_t)C_DIM * C_DIM * 2;
  unsigned short* Wvb = (unsigned short*)(ws + off); off += (size_t)C_DIM * C_DIM * 2;
  unsigned short* Wob = (unsigned short*)(ws + off); off += (size_t)C_DIM * C_DIM * 2;
  unsigned short* qb  = (unsigned short*)(ws + off); off += (size_t)T_DIM * C_DIM * 2;
  unsigned short* kb  = (unsigned short*)(ws + off); off += (size_t)T_DIM * C_DIM * 2;
  unsigned short* vb  = (unsigned short*)(ws + off); off += (size_t)T_DIM * C_DIM * 2;
  unsigned short* ab  = xb;  // alias: xb dead after gemm_qkv

  convert_scores_kernel<<<NSCORE + NCONV, 256, 0, stream>>>(
      x, Wq, Wk, Wv, Wo, Wks, bks, xb, Wqb, Wkb, Wvb, Wob, scores);

  rank_sort_kernel<<<T_DIM / 4, 256, 0, stream>>>(scores, sorted);
  select_topk_kernel<<<T_DIM / 4, 256, 0, stream>>>(sorted, topk);

  gemm_qkv_kernel<<<3 * (T_DIM / GBM) * (C_DIM / GBN), 256, 0, stream>>>(
      xb, Wqb, Wkb, Wvb, bq, bk, bv, qb, kb, vb);

  attn_kernel<<<T_DIM * 4, 256, 0, stream>>>(qb, kb, vb, topk, ab);

  gemm_o_f32_kernel<<<(T_DIM / OBM) * (C_DIM / OBN), 256, 0, stream>>>(
      ab, Wob, bo, out);
}

// Round 16
// 155.108 us; speedup vs baseline: 1.5648x; 1.0034x over previous
//
#include <hip/hip_runtime.h>
#include <hip/hip_bf16.h>
#include <cstdint>
#include <cstddef>

#define T_DIM 2048
#define C_DIM 1024
#define NH 16
#define HS 64
#define KSP 64

// QKV GEMM: 128x64 tile, BK=128, XOR-swizzled LDS, global_load_lds staging
#define GBM 128
#define GBN 64
#define GBK 128
// o-proj GEMM: 64x64 tile (512 blocks = 2/CU)
#define OBM 64
#define OBN 64

typedef short short8 __attribute__((ext_vector_type(8)));
typedef float f32x4 __attribute__((ext_vector_type(4)));
typedef _Float16 half2_t __attribute__((ext_vector_type(2)));

__device__ __forceinline__ float bfu2f(unsigned short u) {
  unsigned v = ((unsigned)u) << 16;
  return __builtin_bit_cast(float, v);
}
__device__ __forceinline__ unsigned short f2bfu(float f) {
  unsigned u = __builtin_bit_cast(unsigned, f);
  unsigned r = (u + 0x7fffu + ((u >> 16) & 1u)) >> 16;
  return (unsigned short)r;
}
__device__ __forceinline__ unsigned short f2h(float f) {
  _Float16 h = (_Float16)f;
  return __builtin_bit_cast(unsigned short, h);
}
__device__ __forceinline__ float bflo(unsigned u) {
  return __builtin_bit_cast(float, u << 16);
}
__device__ __forceinline__ float bfhi(unsigned u) {
  return __builtin_bit_cast(float, u & 0xffff0000u);
}

__device__ __forceinline__ float dot2h(unsigned kbits, unsigned qbits, float acc) {
#if __has_builtin(__builtin_amdgcn_fdot2)
  return __builtin_amdgcn_fdot2(__builtin_bit_cast(half2_t, kbits),
                                __builtin_bit_cast(half2_t, qbits), acc, false);
#else
  half2_t kk = __builtin_bit_cast(half2_t, kbits);
  half2_t qq = __builtin_bit_cast(half2_t, qbits);
  return acc + (float)kk.x * (float)qq.x + (float)kk.y * (float)qq.y;
#endif
}

#define GLOAD_LDS16(gp, lp)                                                  \
  __builtin_amdgcn_global_load_lds(                                          \
      (const __attribute__((address_space(1))) void*)(gp),                   \
      (__attribute__((address_space(3))) void*)(lp), 16, 0, 0)

// ---- launch 1: key_scores (blocks [0,512)) + f32->bf16 conversion (rest) ----
#define NSCORE (T_DIM / 4)  // 512
#define NCONV ((T_DIM * C_DIM + 4 * C_DIM * C_DIM) / 4 / 256)  // 6144
__global__ __launch_bounds__(256) void convert_scores_kernel(
    const float* __restrict__ x, const float* __restrict__ Wq,
    const float* __restrict__ Wk, const float* __restrict__ Wv,
    const float* __restrict__ Wo, const float* __restrict__ Wks,
    const float* __restrict__ bks,
    unsigned short* __restrict__ xb, unsigned short* __restrict__ Wqb,
    unsigned short* __restrict__ Wkb, unsigned short* __restrict__ Wvb,
    unsigned short* __restrict__ Wob, float* __restrict__ scores) {
  if (blockIdx.x < NSCORE) {
    const int t = blockIdx.x * 4 + (threadIdx.x >> 6);
    const int lane = threadIdx.x & 63;
    const float* xrow = x + (size_t)t * C_DIM;
    float acc = 0.f;
    #pragma unroll 4
    for (int i = lane; i < C_DIM; i += 64)
      acc += xrow[i] * Wks[i];
    #pragma unroll
    for (int o = 32; o; o >>= 1) acc += __shfl_xor(acc, o);
    if (lane == 0) scores[t] = acc + bks[0];
    return;
  }
  const int i = (blockIdx.x - NSCORE) * 256 + threadIdx.x;
  const int NX4 = T_DIM * C_DIM / 4;
  const int NW4 = C_DIM * C_DIM / 4;
  const float* src;
  unsigned short* dst;
  int j = i;
  if (j < NX4) { src = x; dst = xb; }
  else {
    j -= NX4;
    int w = j / NW4;
    j -= w * NW4;
    src = (w == 0) ? Wq : (w == 1) ? Wk : (w == 2) ? Wv : Wo;
    dst = (w == 0) ? Wqb : (w == 1) ? Wkb : (w == 2) ? Wvb : Wob;
  }
  float4 f = reinterpret_cast<const float4*>(src)[j];
  ushort4 o;
  o.x = f2bfu(f.x); o.y = f2bfu(f.y); o.z = f2bfu(f.z); o.w = f2bfu(f.w);
  reinterpret_cast<ushort4*>(dst)[j] = o;
}

// ---- GEMM body: 128x64 tile, BK=128; LDS passed in (shared arena) ----
__device__ __forceinline__ void gemm_body_128x64(
    const unsigned short* __restrict__ A, const unsigned short* __restrict__ W,
    f32x4 acc[4][2], int bm, int bn, int tid,
    unsigned short* As, unsigned short* Ws) {
  const int w = tid >> 6, lane = tid & 63;
  const int quad = lane >> 4, r = lane & 15;
  const int wm = (w >> 1) * 64, wn = (w & 1) * 32;
  const int sub = lane >> 4;
  const int c = lane & 15;
  const unsigned short* Arow[8];
  const unsigned short* Wrow[4];
  #pragma unroll
  for (int i = 0; i < 8; ++i) {
    const int row = w * 32 + i * 4 + sub;
    Arow[i] = A + (size_t)(bm * GBM + row) * C_DIM + ((c ^ (row & 7)) * 8);
  }
  #pragma unroll
  for (int i = 0; i < 4; ++i) {
    const int row = w * 16 + i * 4 + sub;
    Wrow[i] = W + (size_t)(bn * GBN + row) * C_DIM + ((c ^ (row & 7)) * 8);
  }
  for (int kb = 0; kb < C_DIM; kb += GBK) {
    #pragma unroll
    for (int i = 0; i < 8; ++i)
      GLOAD_LDS16(Arow[i] + kb, &As[(w * 32 + i * 4) * GBK]);
    #pragma unroll
    for (int i = 0; i < 4; ++i)
      GLOAD_LDS16(Wrow[i] + kb, &Ws[(w * 16 + i * 4) * GBK]);
    __syncthreads();
    #pragma unroll
    for (int ks = 0; ks < 4; ++ks) {
      const int pc = ((ks * 4 + quad) ^ (r & 7)) * 8;
      short8 af[4], bfr[2];
      #pragma unroll
      for (int mi = 0; mi < 4; ++mi)
        af[mi] = *reinterpret_cast<const short8*>(&As[(wm + mi * 16 + r) * GBK + pc]);
      #pragma unroll
      for (int ni = 0; ni < 2; ++ni)
        bfr[ni] = *reinterpret_cast<const short8*>(&Ws[(wn + ni * 16 + r) * GBK + pc]);
      #pragma unroll
      for (int mi = 0; mi < 4; ++mi)
        #pragma unroll
        for (int ni = 0; ni < 2; ++ni)
          acc[mi][ni] = __builtin_amdgcn_mfma_f32_16x16x32_bf16(af[mi], bfr[ni], acc[mi][ni], 0, 0, 0);
    }
    __syncthreads();
  }
}

// ---- launch 2: rank_sort (blocks [0,512)) + fused QKV GEMM (rest).
// Rank and QKV have disjoint deps (both only need launch 1); rank blocks are
// tiny and run alongside the GEMM. LDS arena shared by both paths. ----
#define NRANK (T_DIM / 4)  // 512
__global__ __launch_bounds__(256) void gemm_qkv_rank_kernel(
    const unsigned short* __restrict__ A,
    const unsigned short* __restrict__ Wq, const unsigned short* __restrict__ Wk,
    const unsigned short* __restrict__ Wv,
    const float* __restrict__ bq, const float* __restrict__ bk,
    const float* __restrict__ bv,
    unsigned short* __restrict__ qo, unsigned short* __restrict__ ko,
    unsigned short* __restrict__ vo,
    const float* __restrict__ scores, int* __restrict__ sorted_idx) {
  __shared__ unsigned short lds[(GBM + GBN) * GBK];  // 48 KB arena
  const int tid = threadIdx.x;
  if (blockIdx.x < NRANK) {
    // rank-by-counting sort: one wave per element, lane-parallel scan
    float* ss = reinterpret_cast<float*>(lds);  // first 8 KB of arena
    for (int j = tid; j < T_DIM; j += 256) ss[j] = scores[j];
    __syncthreads();
    const int w = tid >> 6, lane = tid & 63;
    const int i = blockIdx.x * 4 + w;
    const float si = ss[i];
    int rank = 0;
    #pragma unroll
    for (int step = 0; step < T_DIM / 64; ++step) {
      const int j = step * 64 + lane;
      const float sj = ss[j];
      rank += (int)((sj > si) || (sj == si && j < i));
    }
    #pragma unroll
    for (int o = 32; o; o >>= 1) rank += __shfl_xor(rank, o);
    if (lane == 0) sorted_idx[rank] = i;
    return;
  }
  const int bid = blockIdx.x - NRANK;
  const int per = (T_DIM / GBM) * (C_DIM / GBN);  // 256
  const int which = bid / per;
  const int rem = bid % per;
  const int bm = rem / (C_DIM / GBN);
  const int bn = rem % (C_DIM / GBN);
  const unsigned short* W = (which == 0) ? Wq : (which == 1) ? Wk : Wv;
  const float* bias = (which == 0) ? bq : (which == 1) ? bk : bv;
  unsigned short* out = (which == 0) ? qo : (which == 1) ? ko : vo;
  f32x4 acc[4][2] = {};
  gemm_body_128x64(A, W, acc, bm, bn, tid, lds, lds + GBM * GBK);
  const int w = tid >> 6, lane = tid & 63;
  const int quad = lane >> 4, r = lane & 15;
  const int wm = (w >> 1) * 64, wn = (w & 1) * 32;
  #pragma unroll
  for (int mi = 0; mi < 4; ++mi) {
    #pragma unroll
    for (int ni = 0; ni < 2; ++ni) {
      const int col = bn * GBN + wn + ni * 16 + r;
      const float bf = bias[col];
      #pragma unroll
      for (int i = 0; i < 4; ++i) {
        const int row = bm * GBM + wm + mi * 16 + quad * 4 + i;
        const float val = acc[mi][ni][i] + bf;
        // q,k -> f16 (fdot2 path in attn); v -> bf16
        out[(size_t)row * C_DIM + col] = (which == 2) ? f2bfu(val) : f2h(val);
      }
    }
  }
}

// ---- o-proj GEMM body: 64x64 tile, BK=128 ----
__device__ __forceinline__ void gemm_body_64x64(
    const unsigned short* __restrict__ A, const unsigned short* __restrict__ W,
    f32x4 acc[2][2], int bm, int bn, int tid) {
  __shared__ unsigned short As[OBM * GBK];  // 16 KB
  __shared__ unsigned short Ws[OBN * GBK];  // 16 KB
  const int w = tid >> 6, lane = tid & 63;
  const int quad = lane >> 4, r = lane & 15;
  const int wm = (w >> 1) * 32, wn = (w & 1) * 32;
  const int sub = lane >> 4;
  const int c = lane & 15;
  const unsigned short* Arow[4];
  const unsigned short* Wrow[4];
  #pragma unroll
  for (int i = 0; i < 4; ++i) {
    const int row = w * 16 + i * 4 + sub;
    Arow[i] = A + (size_t)(bm * OBM + row) * C_DIM + ((c ^ (row & 7)) * 8);
    Wrow[i] = W + (size_t)(bn * OBN + row) * C_DIM + ((c ^ (row & 7)) * 8);
  }
  for (int kb = 0; kb < C_DIM; kb += GBK) {
    #pragma unroll
    for (int i = 0; i < 4; ++i)
      GLOAD_LDS16(Arow[i] + kb, &As[(w * 16 + i * 4) * GBK]);
    #pragma unroll
    for (int i = 0; i < 4; ++i)
      GLOAD_LDS16(Wrow[i] + kb, &Ws[(w * 16 + i * 4) * GBK]);
    __syncthreads();
    #pragma unroll
    for (int ks = 0; ks < 4; ++ks) {
      const int pc = ((ks * 4 + quad) ^ (r & 7)) * 8;
      short8 af[2], bfr[2];
      #pragma unroll
      for (int mi = 0; mi < 2; ++mi)
        af[mi] = *reinterpret_cast<const short8*>(&As[(wm + mi * 16 + r) * GBK + pc]);
      #pragma unroll
      for (int ni = 0; ni < 2; ++ni)
        bfr[ni] = *reinterpret_cast<const short8*>(&Ws[(wn + ni * 16 + r) * GBK + pc]);
      #pragma unroll
      for (int mi = 0; mi < 2; ++mi)
        #pragma unroll
        for (int ni = 0; ni < 2; ++ni)
          acc[mi][ni] = __builtin_amdgcn_mfma_f32_16x16x32_bf16(af[mi], bfr[ni], acc[mi][ni], 0, 0, 0);
    }
    __syncthreads();
  }
}

// ---- launch 4: output projection GEMM, fp32 out, 64x64 tile ----
__global__ __launch_bounds__(256) void gemm_o_f32_kernel(
    const unsigned short* __restrict__ A, const unsigned short* __restrict__ W,
    const float* __restrict__ bias, float* __restrict__ out) {
  const int tid = threadIdx.x;
  const int bm = blockIdx.x / (C_DIM / OBN);
  const int bn = blockIdx.x % (C_DIM / OBN);
  f32x4 acc[2][2] = {};
  gemm_body_64x64(A, W, acc, bm, bn, tid);
  const int w = tid >> 6, lane = tid & 63;
  const int quad = lane >> 4, r = lane & 15;
  const int wm = (w >> 1) * 32, wn = (w & 1) * 32;
  #pragma unroll
  for (int mi = 0; mi < 2; ++mi) {
    #pragma unroll
    for (int ni = 0; ni < 2; ++ni) {
      const int col = bn * OBN + wn + ni * 16 + r;
      const float bf = bias[col];
      #pragma unroll
      for (int i = 0; i < 4; ++i) {
        const int row = bm * OBM + wm + mi * 16 + quad * 4 + i;
        out[(size_t)row * C_DIM + col] = acc[mi][ni][i] + bf;
      }
    }
  }
}

// ---- launch 3: sparse attention v10 with INLINE top-64 selection.
// Block per (t, head-group); stages sorted (8 KB) once, each wave derives
// its t's selection via ballot scan (redundant across waves, race-free).
// Then Q,K f16 fdot2 phase-1, V bf16 phase-2, all gathers up-front. ----
__global__ __launch_bounds__(256) void attn_kernel(
    const unsigned short* __restrict__ q, const unsigned short* __restrict__ k,
    const unsigned short* __restrict__ v, const int* __restrict__ sorted_idx,
    unsigned short* __restrict__ attn_out) {
  __shared__ int ss[T_DIM];        // 8 KB sorted indices
  __shared__ int off_s[4][KSP];    // 1 KB per-wave selected row offsets
  const int t = blockIdx.x >> 2;
  const int hg = blockIdx.x & 3;
  const int tid = threadIdx.x;
  const int w = tid >> 6, lane = tid & 63;
  const int h = hg * 4 + w;
  for (int i = tid; i < T_DIM; i += 256) {
    int s = sorted_idx[i];
    ss[i] = (s < 0) ? 0 : (s > T_DIM - 1 ? T_DIM - 1 : s);
  }
  __syncthreads();
  // inline selection: each wave computes its t's top-64 into off_s[w]
  if (t <= 63) {
    off_s[w][lane] = ((lane < t) ? lane : t) * C_DIM;
  } else {
    const unsigned long long lt_mask = (1ull << lane) - 1ull;
    int count = 0;
    for (int chunk = 0; chunk < T_DIM / 64 && count < KSP; ++chunk) {
      int s = ss[chunk * 64 + lane];
      bool ok = (s <= t);
      unsigned long long mm = __ballot(ok);
      int pos = count + __popcll(mm & lt_mask);
      if (ok && pos < KSP) off_s[w][pos] = s * C_DIM;
      count += __popcll(mm);
    }
  }
  __builtin_amdgcn_wave_barrier();
  const int c8 = lane & 7;
  const int ksub = lane >> 3;
  const int hbase = h * HS + 8 * c8;
  uint4 qraw = *reinterpret_cast<const uint4*>(q + (size_t)t * C_DIM + hbase);
  int offr[8];
  #pragma unroll
  for (int jj = 0; jj < 8; ++jj) offr[jj] = off_s[w][8 * jj + ksub];
  uint4 kraw[8], vraw[8];
  #pragma unroll
  for (int jj = 0; jj < 8; ++jj)
    kraw[jj] = *reinterpret_cast<const uint4*>(k + offr[jj] + hbase);
  #pragma unroll
  for (int jj = 0; jj < 8; ++jj)
    vraw[jj] = *reinterpret_cast<const uint4*>(v + offr[jj] + hbase);
  // phase 1: logits via f16 dot2, scale post-dot (exact pow2)
  float l[8];
  #pragma unroll
  for (int jj = 0; jj < 8; ++jj) {
    const uint4 raw = kraw[jj];
    float pl = dot2h(raw.x, qraw.x, 0.f);
    pl = dot2h(raw.y, qraw.y, pl);
    pl = dot2h(raw.z, qraw.z, pl);
    pl = dot2h(raw.w, qraw.w, pl);
    pl *= 0.125f;
    pl += __shfl_xor(pl, 1);
    pl += __shfl_xor(pl, 2);
    pl += __shfl_xor(pl, 4);
    l[jj] = pl;
  }
  float m = l[0];
  #pragma unroll
  for (int jj = 1; jj < 8; ++jj) m = fmaxf(m, l[jj]);
  m = fmaxf(m, __shfl_xor(m, 8));
  m = fmaxf(m, __shfl_xor(m, 16));
  m = fmaxf(m, __shfl_xor(m, 32));
  float sum = 0.f;
  #pragma unroll
  for (int jj = 0; jj < 8; ++jj) {
    l[jj] = __expf(l[jj] - m);
    sum += l[jj];
  }
  sum += __shfl_xor(sum, 8);
  sum += __shfl_xor(sum, 16);
  sum += __shfl_xor(sum, 32);
  const float rs = 1.0f / sum;
  // phase 2: weighted V (bf16) sum
  float a[8] = {0.f, 0.f, 0.f, 0.f, 0.f, 0.f, 0.f, 0.f};
  #pragma unroll
  for (int jj = 0; jj < 8; ++jj) {
    const uint4 raw = vraw[jj];
    const float p = l[jj] * rs;
    a[0] += p * bflo(raw.x); a[1] += p * bfhi(raw.x);
    a[2] += p * bflo(raw.y); a[3] += p * bfhi(raw.y);
    a[4] += p * bflo(raw.z); a[5] += p * bfhi(raw.z);
    a[6] += p * bflo(raw.w); a[7] += p * bfhi(raw.w);
  }
  #pragma unroll
  for (int o = 8; o <= 32; o <<= 1) {
    #pragma unroll
    for (int z = 0; z < 8; ++z) a[z] += __shfl_xor(a[z], o);
  }
  if (ksub == 0) {
    ushort4 o0, o1;
    o0.x = f2bfu(a[0]); o0.y = f2bfu(a[1]); o0.z = f2bfu(a[2]); o0.w = f2bfu(a[3]);
    o1.x = f2bfu(a[4]); o1.y = f2bfu(a[5]); o1.z = f2bfu(a[6]); o1.w = f2bfu(a[7]);
    ushort4* dst = reinterpret_cast<ushort4*>(attn_out + (size_t)t * C_DIM + hbase);
    dst[0] = o0;
    dst[1] = o1;
  }
}

extern "C" void kernel_launch(void* const* d_in, const int* in_sizes, int n_in,
                              void* d_out, int out_size, void* d_ws, size_t ws_size,
                              hipStream_t stream) {
  const float* x   = (const float*)d_in[0];
  const float* Wq  = (const float*)d_in[1];
  const float* bq  = (const float*)d_in[2];
  const float* Wk  = (const float*)d_in[3];
  const float* bk  = (const float*)d_in[4];
  const float* Wv  = (const float*)d_in[5];
  const float* bv  = (const float*)d_in[6];
  const float* Wo  = (const float*)d_in[7];
  const float* bo  = (const float*)d_in[8];
  const float* Wks = (const float*)d_in[9];
  const float* bks = (const float*)d_in[10];
  float* out = (float*)d_out;

  char* ws = (char*)d_ws;
  size_t off = 0;
  float* scores = (float*)(ws + off); off += 8192;
  int*   sorted = (int*)(ws + off);   off += 8192;
  unsigned short* xb  = (unsigned short*)(ws + off); off += (size_t)T_DIM * C_DIM * 2;
  unsigned short* Wqb = (unsigned short*)(ws + off); off += (size_t)C_DIM * C_DIM * 2;
  unsigned short* Wkb = (unsigned short*)(ws + off); off += (size_t)C_DIM * C_DIM * 2;
  unsigned short* Wvb = (unsigned short*)(ws + off); off += (size_t)C_DIM * C_DIM * 2;
  unsigned short* Wob = (unsigned short*)(ws + off); off += (size_t)C_DIM * C_DIM * 2;
  unsigned short* qb  = (unsigned short*)(ws + off); off += (size_t)T_DIM * C_DIM * 2;
  unsigned short* kb  = (unsigned short*)(ws + off); off += (size_t)T_DIM * C_DIM * 2;
  unsigned short* vb  = (unsigned short*)(ws + off); off += (size_t)T_DIM * C_DIM * 2;
  unsigned short* ab  = xb;  // alias: xb dead after gemm_qkv

  // launch 1: conversion + scores
  convert_scores_kernel<<<NSCORE + NCONV, 256, 0, stream>>>(
      x, Wq, Wk, Wv, Wo, Wks, bks, xb, Wqb, Wkb, Wvb, Wob, scores);

  // launch 2: rank-sort (512 blocks) + fused QKV GEMM (768 blocks)
  gemm_qkv_rank_kernel<<<NRANK + 3 * (T_DIM / GBM) * (C_DIM / GBN), 256, 0,
                         stream>>>(
      xb, Wqb, Wkb, Wvb, bq, bk, bv, qb, kb, vb, scores, sorted);

  // launch 3: attention with inline top-64 selection
  attn_kernel<<<T_DIM * 4, 256, 0, stream>>>(qb, kb, vb, sorted, ab);

  // launch 4: output projection
  gemm_o_f32_kernel<<<(T_DIM / OBM) * (C_DIM / OBN), 256, 0, stream>>>(
      ab, Wob, bo, out);
}